// Round 12
// baseline (237.097 us; speedup 1.0000x reference)
//
#include <hip/hip_runtime.h>
#include <hip/hip_bf16.h>

// Problem constants
#define NROWS 16384   // 8*2048 tokens
#define DM    1024    // d_model
#define CD    64      // code depth
#define NC    2048    // num codes
#define KC    2047    // codes excluding index 0
#define NB    8       // batch
#define DECAY 0.99f

#define K3_BLOCKS 512

// d_out layout (floats, concatenated in reference return order)
#define OUT_HARD   0
#define OUT_IDX    1048576
#define OUT_COMMIT 1064960
#define OUT_EMB    1064961
#define OUT_CB     1064962
#define OUT_CS     1196034
#define OUT_CSUM   1198082

// d_ws layout (float offsets)
#define WS_Z      0                          // 1048576 f
#define WS_CN2    1048576                    // 2048 f ([2047]=+INF pad)
#define WS_BINC   1050624                    // 2048 u32
#define WS_SUMS   1052672                    // 131072 f
#define WS_CDIST  1183744                    // 8*2047 u32
#define WS_COMMIT 1200120                    // 512 f per-block partials
#define WS_ZN2    1200632                    // 16384 f
#define WS_N      1217016                    // 1 f (+3 pad)
#define WS_PART   1298940                    // 4*16384*64 f split-K partials (k1 only)
// MFMA-path scratch ALIASES PART (dead after k1_reduce):
#define WS_ZB2    WS_PART                    // 16384*64 bf16 (524288 f)
#define WS_CBB2   (WS_PART + 524288)         // 2048*64 bf16 (65536 f)
#define WS_CAND   (WS_PART + 589824)         // 16384*192 f (96 (v,i) pairs/row)
#define WS_IDXM2  (WS_PART + 3735552)        // 16384 i32 final idx
// legacy f32-path scratch (also aliases PART):
#define WS_BV     WS_PART                    // 4*16384 f  per-quarter best value
#define WS_BI     (WS_PART + 65536)          // 4*16384 i32 per-quarter best idx (+1)

#define F32_INF_BITS 0x7F800000u

typedef __attribute__((ext_vector_type(8))) short short8;
typedef __attribute__((ext_vector_type(4))) float f32x4;

__device__ inline unsigned short f2bf(float f) {
  __hip_bfloat16 h = __float2bfloat16(f);   // RNE
  return *reinterpret_cast<unsigned short*>(&h);
}

// ---------------------------------------------------------------- K0: init
__global__ __launch_bounds__(256) void k0_init(const float* __restrict__ cb,
                                               float* __restrict__ ws) {
  int i = blockIdx.x * 256 + threadIdx.x;
  if (i < NC * CD) (ws + WS_SUMS)[i] = 0.0f;
  if (i < NC) {
    ((unsigned*)(ws + WS_BINC))[i] = 0u;
    float cn2;
    if (i < KC) {
      const float* c = cb + (size_t)(i + 1) * CD;
      float s0 = 0.f, s1 = 0.f;
      #pragma unroll
      for (int d = 0; d < CD; d += 2) { s0 = fmaf(c[d], c[d], s0); s1 = fmaf(c[d+1], c[d+1], s1); }
      cn2 = s0 + s1;
    } else {
      cn2 = __uint_as_float(F32_INF_BITS);
    }
    (ws + WS_CN2)[i] = cn2;
  }
  if (i < NB * KC) ((unsigned*)(ws + WS_CDIST))[i] = F32_INF_BITS;
}

// ------------- K1 (split-K): partial[kslice] = x[:,ks*256:+256] @ W^T slice
// 256 thr/block, 8 rows x 4 cols/thread, BK=64, grid 512 (proven R11).
__global__ __launch_bounds__(256) void k1_split(const float* __restrict__ x,
                                                const float* __restrict__ W,
                                                float* __restrict__ ws) {
  __shared__ float xs[64][132];   // [k][row'] swizzled
  __shared__ float wls[64][68];   // [k][col]
  const int t = threadIdx.x;             // 0..255
  const int ks = blockIdx.x & 3;
  const int row0 = (blockIdx.x >> 2) * 128;
  const int kbase = ks * 256;
  const int tx = t & 15, ty = t >> 4;    // tx: 16 col-groups(x4), ty: 16 row-groups(x8)
  const int sseg = t & 15, srow = t >> 4;

  float4 px[8], pw[4];
  auto ld = [&](int kt) {
    const int kk = kbase + kt * 64;
    #pragma unroll
    for (int it = 0; it < 8; ++it)
      px[it] = *(const float4*)(x + (size_t)(row0 + srow + 16 * it) * DM + kk + sseg * 4);
    #pragma unroll
    for (int it = 0; it < 4; ++it)
      pw[it] = *(const float4*)(W + (size_t)(srow + 16 * it) * DM + kk + sseg * 4);
  };
  ld(0);

  float acc[8][4];
  #pragma unroll
  for (int i = 0; i < 8; i++)
    #pragma unroll
    for (int j = 0; j < 4; j++) acc[i][j] = 0.f;

  for (int kt = 0; kt < 4; ++kt) {
    __syncthreads();
    const int sg4 = sseg * 4;
    #pragma unroll
    for (int it = 0; it < 8; ++it) {
      const int cpos = (srow + 16 * it) ^ ((sseg & 3) << 3);
      xs[sg4 + 0][cpos] = px[it].x; xs[sg4 + 1][cpos] = px[it].y;
      xs[sg4 + 2][cpos] = px[it].z; xs[sg4 + 3][cpos] = px[it].w;
    }
    #pragma unroll
    for (int it = 0; it < 4; ++it) {
      const int wcol = srow + 16 * it;
      wls[sg4 + 0][wcol] = pw[it].x; wls[sg4 + 1][wcol] = pw[it].y;
      wls[sg4 + 2][wcol] = pw[it].z; wls[sg4 + 3][wcol] = pw[it].w;
    }
    __syncthreads();
    if (kt < 3) ld(kt + 1);

    #pragma unroll 8
    for (int dl = 0; dl < 64; ++dl) {
      const int xcol = (ty * 8) ^ (((dl >> 2) & 3) << 3);
      float4 xv0 = *(const float4*)(&xs[dl][xcol]);
      float4 xv1 = *(const float4*)(&xs[dl][xcol + 4]);
      float4 wv  = *(const float4*)(&wls[dl][tx * 4]);
      float xz[8] = {xv0.x, xv0.y, xv0.z, xv0.w, xv1.x, xv1.y, xv1.z, xv1.w};
      float wc[4] = {wv.x, wv.y, wv.z, wv.w};
      #pragma unroll
      for (int i = 0; i < 8; i++)
        #pragma unroll
        for (int j = 0; j < 4; j++)
          acc[i][j] = fmaf(xz[i], wc[j], acc[i][j]);
    }
  }

  float* part = ws + WS_PART + (size_t)ks * NROWS * CD;
  #pragma unroll
  for (int i = 0; i < 8; i++) {
    const int row = row0 + ty * 8 + i;
    float4 v; v.x = acc[i][0]; v.y = acc[i][1]; v.z = acc[i][2]; v.w = acc[i][3];
    *(float4*)(part + (size_t)row * CD + tx * 4) = v;
  }
}

// ------------- K1r: sum 4 partials + bias, row-normalize, write z/zn2
__global__ __launch_bounds__(256) void k1_reduce(const float* __restrict__ bdown,
                                                 float* __restrict__ ws) {
  const int t = threadIdx.x;
  const int tx = t & 15, ty = t >> 4;
  const int row = blockIdx.x * 16 + ty;
  const float* part = ws + WS_PART;
  const size_t off = (size_t)row * CD + tx * 4;

  float4 v0 = *(const float4*)(part + off);
  float4 v1 = *(const float4*)(part + (size_t)1 * NROWS * CD + off);
  float4 v2 = *(const float4*)(part + (size_t)2 * NROWS * CD + off);
  float4 v3 = *(const float4*)(part + (size_t)3 * NROWS * CD + off);
  float4 b  = *(const float4*)(bdown + tx * 4);
  float4 v;
  v.x = (v0.x + v1.x) + (v2.x + v3.x) + b.x;
  v.y = (v0.y + v1.y) + (v2.y + v3.y) + b.y;
  v.z = (v0.z + v1.z) + (v2.z + v3.z) + b.z;
  v.w = (v0.w + v1.w) + (v2.w + v3.w) + b.w;

  float ss = v.x * v.x + v.y * v.y + v.z * v.z + v.w * v.w;
  #pragma unroll
  for (int m = 1; m < 16; m <<= 1) ss += __shfl_xor(ss, m, 64);
  float inv = 1.0f / sqrtf(ss);   // uniform per-row scale: argmin-safe
  float4 zv; zv.x = v.x * inv; zv.y = v.y * inv; zv.z = v.z * inv; zv.w = v.w * inv;
  *(float4*)(ws + WS_Z + off) = zv;
  if (tx == 0) (ws + WS_ZN2)[row] = ss * inv * inv;
}

// ------------- K1 legacy (used only if ws too small for split-K partials)
__global__ __launch_bounds__(256) void k1_down(const float* __restrict__ x,
                                               const float* __restrict__ W,
                                               const float* __restrict__ bdown,
                                               float* __restrict__ ws) {
  __shared__ float xs[64][68];
  __shared__ float wls[64][68];
  const int t = threadIdx.x;
  const int row0 = blockIdx.x * 64;
  const int tx = t & 15, ty = t >> 4;

  int pr[4], pseg[4];
  #pragma unroll
  for (int it = 0; it < 4; ++it) { int c = t + it * 256; pr[it] = c >> 4; pseg[it] = c & 15; }

  float4 px[4], pw[4];
  #pragma unroll
  for (int it = 0; it < 4; ++it) {
    px[it] = *(const float4*)(x + (size_t)(row0 + pr[it]) * DM + pseg[it] * 4);
    pw[it] = *(const float4*)(W + (size_t)pr[it] * DM + pseg[it] * 4);
  }

  float acc[4][4];
  #pragma unroll
  for (int i = 0; i < 4; i++)
    #pragma unroll
    for (int j = 0; j < 4; j++) acc[i][j] = 0.f;

  for (int kt = 0; kt < 16; ++kt) {
    __syncthreads();
    #pragma unroll
    for (int it = 0; it < 4; ++it) {
      *(float4*)(&xs[pr[it]][pseg[it] * 4]) = px[it];
      *(float4*)(&wls[pr[it]][pseg[it] * 4]) = pw[it];
    }
    __syncthreads();
    if (kt < 15) {
      const int k0 = (kt + 1) * 64;
      #pragma unroll
      for (int it = 0; it < 4; ++it) {
        px[it] = *(const float4*)(x + (size_t)(row0 + pr[it]) * DM + k0 + pseg[it] * 4);
        pw[it] = *(const float4*)(W + (size_t)pr[it] * DM + k0 + pseg[it] * 4);
      }
    }
    #pragma unroll 4
    for (int k = 0; k < 64; k += 4) {
      float4 xv[4], wv[4];
      #pragma unroll
      for (int i = 0; i < 4; i++) xv[i] = *(const float4*)(&xs[ty * 4 + i][k]);
      #pragma unroll
      for (int j = 0; j < 4; j++) wv[j] = *(const float4*)(&wls[tx * 4 + j][k]);
      #pragma unroll
      for (int i = 0; i < 4; i++)
        #pragma unroll
        for (int j = 0; j < 4; j++)
          acc[i][j] = fmaf(xv[i].x, wv[j].x, fmaf(xv[i].y, wv[j].y,
                      fmaf(xv[i].z, wv[j].z, fmaf(xv[i].w, wv[j].w, acc[i][j]))));
    }
  }

  #pragma unroll
  for (int j = 0; j < 4; j++) {
    float bj = bdown[tx * 4 + j];
    #pragma unroll
    for (int i = 0; i < 4; i++) acc[i][j] += bj;
  }

  float* z = ws + WS_Z;
  float* zn2 = ws + WS_ZN2;
  #pragma unroll
  for (int i = 0; i < 4; i++) {
    float ss = acc[i][0] * acc[i][0] + acc[i][1] * acc[i][1] +
               acc[i][2] * acc[i][2] + acc[i][3] * acc[i][3];
    #pragma unroll
    for (int m = 1; m < 16; m <<= 1) ss += __shfl_xor(ss, m, 64);
    float inv = 1.0f / sqrtf(ss);
    float4 zv;
    zv.x = acc[i][0] * inv; zv.y = acc[i][1] * inv;
    zv.z = acc[i][2] * inv; zv.w = acc[i][3] * inv;
    int row = row0 + ty * 4 + i;
    *(float4*)(z + (size_t)row * CD + tx * 4) = zv;
    if (tx == 0) zn2[row] = ss * inv * inv;
  }
}

// ------------- K_CVT: z -> bf16 zb; cb(codes 1..2047) -> bf16 cbb (pad 0)
// Runs AFTER k1_reduce (PART dead -> zb/cbb alias PART safely).
__global__ __launch_bounds__(256) void k_cvt(const float* __restrict__ cb,
                                             float* __restrict__ ws) {
  const int i = blockIdx.x * 256 + threadIdx.x;   // each handles 8 elements
  unsigned short u[8];
  if (i < NROWS * CD / 8) {
    const float* src = ws + WS_Z + (size_t)i * 8;
    #pragma unroll
    for (int e = 0; e < 8; ++e) u[e] = f2bf(src[e]);
    *(short8*)((unsigned short*)(ws + WS_ZB2) + (size_t)i * 8) = *(short8*)u;
  } else if (i < NROWS * CD / 8 + NC * CD / 8) {
    const int j = i - NROWS * CD / 8;
    #pragma unroll
    for (int e = 0; e < 8; ++e) {
      const int f = j * 8 + e;                    // cbb flat idx: code*64+d
      u[e] = (f < KC * CD) ? f2bf(cb[f + CD]) : (unsigned short)0;
    }
    *(short8*)((unsigned short*)(ws + WS_CBB2) + (size_t)j * 8) = *(short8*)u;
  }
}

// ---- K2M: bf16 MFMA coarse distance pass. 2048 blocks x 64 thr (1 wave):
// block = (rowgrp 16 rows) x (code half 1024). Per lane: top-3 candidates
// per its 4 C-rows + colmin -> global cdist. No LDS, no barriers.
// A frag: lane l holds zb[row0+(l&15)][ (l>>4)*8 .. +7 ] (+32 for K-chunk 2).
// B frag: lane l holds cbb[tile*16+(l&15)][ (l>>4)*8 .. +7 ] (+32).
// C/D: lane l, reg q -> row (l>>4)*4+q, col l&15  [verified m89].
__global__ __launch_bounds__(64) void k2m_dist(float* __restrict__ ws) {
  const int l = threadIdx.x;
  const int half = blockIdx.x & 1;
  const int rg = blockIdx.x >> 1;          // 0..1023
  const int row0 = rg * 16;
  const int batch = row0 >> 11;
  const unsigned short* zb = (const unsigned short*)(ws + WS_ZB2);
  const unsigned short* cbb = (const unsigned short*)(ws + WS_CBB2);
  const float* cn2p = ws + WS_CN2;
  unsigned* cdist = (unsigned*)(ws + WS_CDIST) + (size_t)batch * KC;

  const int col = l & 15, kb = l >> 4;
  const size_t za = (size_t)(row0 + col) * CD + kb * 8;   // A row = l&15
  short8 A0 = *(const short8*)(zb + za);
  short8 A1 = *(const short8*)(zb + za + 32);

  float zn2q[4];
  #pragma unroll
  for (int q = 0; q < 4; ++q) zn2q[q] = (ws + WS_ZN2)[row0 + kb * 4 + q];

  float bv[4][3]; int bi[4][3];
  #pragma unroll
  for (int q = 0; q < 4; ++q)
    #pragma unroll
    for (int s = 0; s < 3; ++s) { bv[q][s] = __uint_as_float(F32_INF_BITS); bi[q][s] = KC; }

  const int t0 = half * 64;
  short8 B0, B1; float c2;
  {
    const size_t ca = (size_t)(t0 * 16 + col) * CD + kb * 8;
    B0 = *(const short8*)(cbb + ca);
    B1 = *(const short8*)(cbb + ca + 32);
    c2 = cn2p[t0 * 16 + col];
  }

  for (int tt = 0; tt < 64; ++tt) {
    const int tile = t0 + tt;
    short8 nB0, nB1; float nc2 = 0.f;
    if (tt < 63) {
      const size_t ca = (size_t)((tile + 1) * 16 + col) * CD + kb * 8;
      nB0 = *(const short8*)(cbb + ca);
      nB1 = *(const short8*)(cbb + ca + 32);
      nc2 = cn2p[(tile + 1) * 16 + col];
    }
    f32x4 acc = {0.f, 0.f, 0.f, 0.f};
    acc = __builtin_amdgcn_mfma_f32_16x16x32_bf16(A0, B0, acc, 0, 0, 0);
    acc = __builtin_amdgcn_mfma_f32_16x16x32_bf16(A1, B1, acc, 0, 0, 0);

    const int code = tile * 16 + col;      // 0-based code id
    float cmin = __uint_as_float(F32_INF_BITS);
    #pragma unroll
    for (int q = 0; q < 4; ++q) {
      const float s = fmaf(-2.f, acc[q], c2);
      if (s < bv[q][0]) {
        bv[q][2] = bv[q][1]; bi[q][2] = bi[q][1];
        bv[q][1] = bv[q][0]; bi[q][1] = bi[q][0];
        bv[q][0] = s;        bi[q][0] = code;
      } else if (s < bv[q][1]) {
        bv[q][2] = bv[q][1]; bi[q][2] = bi[q][1];
        bv[q][1] = s;        bi[q][1] = code;
      } else if (s < bv[q][2]) {
        bv[q][2] = s;        bi[q][2] = code;
      }
      float v = zn2q[q] + s;
      v = v < 0.f ? 0.f : v;
      cmin = v < cmin ? v : cmin;
    }
    cmin = fminf(cmin, __shfl_xor(cmin, 16, 64));
    cmin = fminf(cmin, __shfl_xor(cmin, 32, 64));
    if (l < 16 && code < KC) atomicMin(&cdist[code], __float_as_uint(cmin));
    B0 = nB0; B1 = nB1; c2 = nc2;
  }

  // candidate write-out: row*192 + half*96 + col*6 (+slot*2): (v, code)
  float* cand = ws + WS_CAND;
  #pragma unroll
  for (int q = 0; q < 4; ++q) {
    const int row = row0 + kb * 4 + q;
    float* p = cand + (size_t)row * 192 + half * 96 + col * 6;
    #pragma unroll
    for (int s = 0; s < 3; ++s) {
      float2 e; e.x = bv[q][s]; e.y = __int_as_float(bi[q][s]);
      *(float2*)(p + s * 2) = e;
    }
  }
}

// ---- K2M-R: exact f32 rescore of candidates within the bf16 error margin.
// |score_bf16 - score_f32| <= 2*(2^-8*||z||*||c|| + accum) < 0.01; any code
// tied-or-better than the f32 min satisfies v_bf16 <= min_bf16 + 0.02 (proof:
// s16(j) <= s32(j)+eps <= s32(j*)+eps <= s16(j*)+2eps <= min16+2eps).
// f32 chain = d-ascending fmaf, identical to the proven f32 k2 chain.
__global__ __launch_bounds__(256) void k2m_rescore(const float* __restrict__ cb,
                                                   float* __restrict__ ws,
                                                   float* __restrict__ out) {
  const int row = blockIdx.x * 256 + threadIdx.x;   // grid 64
  const float* cand = ws + WS_CAND + (size_t)row * 192;
  float mn = __uint_as_float(F32_INF_BITS);
  for (int s = 0; s < 96; ++s) mn = fminf(mn, cand[s * 2]);
  const float thr = mn + 0.02f;

  float zr[64];
  {
    const float* z = ws + WS_Z + (size_t)row * CD;
    #pragma unroll
    for (int c4 = 0; c4 < 16; ++c4) {
      float4 v = *(const float4*)(z + c4 * 4);
      zr[c4 * 4 + 0] = v.x; zr[c4 * 4 + 1] = v.y;
      zr[c4 * 4 + 2] = v.z; zr[c4 * 4 + 3] = v.w;
    }
  }

  float bestv = __uint_as_float(F32_INF_BITS);
  int besti = 0x7FFFFFFF;
  for (int s = 0; s < 96; ++s) {
    const float v = cand[s * 2];
    if (v <= thr) {
      const int code = __float_as_int(cand[s * 2 + 1]);
      if (code < KC) {
        const float* c = cb + (size_t)(code + 1) * CD;
        float dot = 0.f;
        #pragma unroll
        for (int d = 0; d < 64; ++d) dot = fmaf(zr[d], c[d], dot);
        const float sc = fmaf(-2.f, dot, (ws + WS_CN2)[code]);
        if (sc < bestv || (sc == bestv && code < besti)) { bestv = sc; besti = code; }
      }
    }
  }
  const int idx = besti + 1;
  ((int*)(ws + WS_IDXM2))[row] = idx;
  out[OUT_IDX + row] = (float)idx;
}

// ---- K2 legacy f32 (fallback path; proven 70.7us)
__global__ __launch_bounds__(512) void k2_dist(const float* __restrict__ cbp,
                                               float* __restrict__ ws) {
  __shared__ float zT[64][132];
  __shared__ float cT[64][132];
  __shared__ float cn2s[128];
  __shared__ float zn2s[128];
  __shared__ unsigned colmin[128];

  const int t = threadIdx.x;
  const int gq = blockIdx.x & 3;
  const int rt = blockIdx.x >> 2;
  const int row0 = rt << 7;
  const int batch = rt >> 4;
  const int tx = t & 31, ty = t >> 5;
  const float* z = ws + WS_Z;
  const float* cn2p = ws + WS_CN2;
  unsigned* cdist = (unsigned*)(ws + WS_CDIST) + (size_t)batch * KC;

  if (t < 128) zn2s[t] = (ws + WS_ZN2)[row0 + t];

  {
    const int sr = t >> 2, sp = t & 3;
    float4 v[4];
    #pragma unroll
    for (int it = 0; it < 4; ++it)
      v[it] = *(const float4*)(z + (size_t)(row0 + sr) * CD + (sp + 4 * it) * 4);
    #pragma unroll
    for (int it = 0; it < 4; ++it) {
      const int sg4 = (sp + 4 * it) * 4;
      zT[sg4 + 0][sr] = v[it].x; zT[sg4 + 1][sr] = v[it].y;
      zT[sg4 + 2][sr] = v[it].z; zT[sg4 + 3][sr] = v[it].w;
    }
  }

  const int cr = t >> 2, cp = t & 3;
  const int ccol = cr ^ (((cr >> 5) & 3) << 2);
  float4 pc[4];
  auto ldc = [&](int lt) {
    const int code = gq * 512 + lt * 128 + cr;
    #pragma unroll
    for (int it = 0; it < 4; ++it)
      pc[it] = (code < KC) ? *(const float4*)(cbp + (size_t)(code + 1) * CD + (cp + 4 * it) * 4)
                           : make_float4(0.f, 0.f, 0.f, 0.f);
  };
  ldc(0);

  float bestv[8];
  int besti[8];
  #pragma unroll
  for (int i = 0; i < 8; i++) { bestv[i] = __uint_as_float(F32_INF_BITS); besti[i] = 0; }

  const int ccol0 = (tx * 4) ^ (((tx >> 3) & 3) << 2);

  for (int lt = 0; lt < 4; ++lt) {
    __syncthreads();
    #pragma unroll
    for (int it = 0; it < 4; ++it) {
      const int sg4 = (cp + 4 * it) * 4;
      cT[sg4 + 0][ccol] = pc[it].x; cT[sg4 + 1][ccol] = pc[it].y;
      cT[sg4 + 2][ccol] = pc[it].z; cT[sg4 + 3][ccol] = pc[it].w;
    }
    if (t < 128) {
      cn2s[t] = cn2p[gq * 512 + lt * 128 + t];
      colmin[t] = F32_INF_BITS;
    }
    __syncthreads();
    if (lt < 3) ldc(lt + 1);

    float acc[8][4];
    #pragma unroll
    for (int i = 0; i < 8; i++)
      #pragma unroll
      for (int j = 0; j < 4; j++) acc[i][j] = 0.f;

    #pragma unroll 8
    for (int d = 0; d < 64; ++d) {
      float4 za = *(const float4*)(&zT[d][ty * 8]);
      float4 zb = *(const float4*)(&zT[d][ty * 8 + 4]);
      float4 cv = *(const float4*)(&cT[d][ccol0]);
      float zz[8] = {za.x, za.y, za.z, za.w, zb.x, zb.y, zb.z, zb.w};
      float cc[4] = {cv.x, cv.y, cv.z, cv.w};
      #pragma unroll
      for (int i = 0; i < 8; i++)
        #pragma unroll
        for (int j = 0; j < 4; j++)
          acc[i][j] = fmaf(zz[i], cc[j], acc[i][j]);
    }

    const int jbase = gq * 512 + lt * 128;
    #pragma unroll
    for (int jl = 0; jl < 4; ++jl) {
      const int jloc = tx * 4 + jl;
      const int jg = jbase + jloc;
      const float c2 = cn2s[jloc];
      float colv = __uint_as_float(F32_INF_BITS);
      #pragma unroll
      for (int i = 0; i < 8; ++i) {
        float s = fmaf(-2.f, acc[i][jl], c2);
        if (s < bestv[i]) { bestv[i] = s; besti[i] = jg; }
        float v = zn2s[ty * 8 + i] + s;
        v = v < 0.f ? 0.f : v;
        colv = v < colv ? v : colv;
      }
      colv = fminf(colv, __shfl_xor(colv, 32, 64));
      if ((t & 32) == 0) atomicMin(&colmin[jloc], __float_as_uint(colv));
    }
    __syncthreads();
    if (t < 128) {
      const int jg2 = jbase + t;
      if (jg2 < KC) atomicMin(&cdist[jg2], colmin[t]);
    }
  }

  #pragma unroll
  for (int m = 1; m <= 16; m <<= 1) {
    #pragma unroll
    for (int i = 0; i < 8; i++) {
      float ov = __shfl_xor(bestv[i], m, 64);
      int oi = __shfl_xor(besti[i], m, 64);
      if (ov < bestv[i] || (ov == bestv[i] && oi < besti[i])) { bestv[i] = ov; besti[i] = oi; }
    }
  }
  if (tx == 0) {
    #pragma unroll
    for (int i = 0; i < 8; i++) {
      const int row = row0 + ty * 8 + i;
      (ws + WS_BV)[(size_t)gq * NROWS + row] = bestv[i];
      ((int*)(ws + WS_BI))[(size_t)gq * NROWS + row] = besti[i] + 1;
    }
  }
}

// ------- K3M: gather + commitment + scatter, idx precomputed (MFMA path)
__global__ __launch_bounds__(256) void k3m_scatter(const float* __restrict__ cb,
                                                   float* __restrict__ ws,
                                                   float* __restrict__ out) {
  const int t = threadIdx.x;
  const int lane = t & 63;
  const int w = t >> 6;
  const int rowbase = blockIdx.x * 32 + w * 8;
  const float* z = ws + WS_Z;

  const int myidx = ((const int*)(ws + WS_IDXM2))[rowbase + (lane & 7)];

  float sq = 0.f;
  #pragma unroll
  for (int r = 0; r < 8; ++r) {
    const int idx = __shfl(myidx, r, 8);
    const int row = rowbase + r;
    const float c = cb[(size_t)idx * CD + lane];
    const float zv = z[(size_t)row * CD + lane];
    out[OUT_HARD + (size_t)row * CD + lane] = zv + (c - zv);
    const float d = c - zv;
    sq = fmaf(d, d, sq);
    atomicAdd(ws + WS_SUMS + (size_t)idx * CD + lane, zv);
    if (lane == 0) atomicAdd((unsigned*)(ws + WS_BINC) + idx, 1u);
  }

  __shared__ float red[4];
  #pragma unroll
  for (int m = 1; m < 64; m <<= 1) sq += __shfl_xor(sq, m, 64);
  if (lane == 0) red[w] = sq;
  __syncthreads();
  if (t == 0) (ws + WS_COMMIT)[blockIdx.x] = red[0] + red[1] + red[2] + red[3];
}

// ------- K3 legacy: inline quarter-argmin merge + gather + scatter
__global__ __launch_bounds__(256) void k3_scatter(const float* __restrict__ cb,
                                                  float* __restrict__ ws,
                                                  float* __restrict__ out) {
  const int t = threadIdx.x;
  const int lane = t & 63;
  const int w = t >> 6;
  const int rowbase = blockIdx.x * 32 + w * 8;
  const float* z = ws + WS_Z;

  const int myrow = rowbase + (lane & 7);
  float bv = (ws + WS_BV)[myrow];
  int myidx = ((const int*)(ws + WS_BI))[myrow];
  #pragma unroll
  for (int g2 = 1; g2 < 4; ++g2) {
    float v = (ws + WS_BV)[(size_t)g2 * NROWS + myrow];
    int i2 = ((const int*)(ws + WS_BI))[(size_t)g2 * NROWS + myrow];
    if (v < bv) { bv = v; myidx = i2; }
  }
  if (lane < 8) out[OUT_IDX + myrow] = (float)myidx;

  float sq = 0.f;
  #pragma unroll
  for (int r = 0; r < 8; ++r) {
    const int idx = __shfl(myidx, r, 8);
    const int row = rowbase + r;
    const float c = cb[(size_t)idx * CD + lane];
    const float zv = z[(size_t)row * CD + lane];
    out[OUT_HARD + (size_t)row * CD + lane] = zv + (c - zv);
    const float d = c - zv;
    sq = fmaf(d, d, sq);
    atomicAdd(ws + WS_SUMS + (size_t)idx * CD + lane, zv);
    if (lane == 0) atomicAdd((unsigned*)(ws + WS_BINC) + idx, 1u);
  }

  __shared__ float red[4];
  #pragma unroll
  for (int m = 1; m < 64; m <<= 1) sq += __shfl_xor(sq, m, 64);
  if (lane == 0) red[w] = sq;
  __syncthreads();
  if (t == 0) (ws + WS_COMMIT)[blockIdx.x] = red[0] + red[1] + red[2] + red[3];
}

// --------- K4a: new_cs + n + losses (single block, small data only)
__global__ __launch_bounds__(1024) void k4a_stats(const float* __restrict__ cs_in,
                                                  float* __restrict__ ws,
                                                  float* __restrict__ out) {
  __shared__ float red[1024];
  const int t = threadIdx.x;
  const unsigned* binc = (const unsigned*)(ws + WS_BINC);

  float npart = 0.f;
  #pragma unroll
  for (int i = t; i < NC; i += 1024) {
    float nc = DECAY * cs_in[i] + (1.f - DECAY) * (float)binc[i];
    out[OUT_CS + i] = nc;
    npart += nc;
  }
  red[t] = npart; __syncthreads();
  for (int s = 512; s > 0; s >>= 1) { if (t < s) red[t] += red[t + s]; __syncthreads(); }
  if (t == 0) (ws + WS_N)[0] = red[0];
  __syncthreads();

  float cpart = 0.f;
  for (int j = t; j < K3_BLOCKS; j += 1024) cpart += (ws + WS_COMMIT)[j];
  red[t] = cpart; __syncthreads();
  for (int s = 512; s > 0; s >>= 1) { if (t < s) red[t] += red[t + s]; __syncthreads(); }
  float commit = red[0]; __syncthreads();

  const unsigned* cdist = (const unsigned*)(ws + WS_CDIST);
  float lsum = 0.f, ccount = 0.f;
  for (int j = t; j < KC; j += 1024) {
    if (binc[j + 1] == 0u) {
      ccount += 1.f;
      float srow = 0.f;
      #pragma unroll
      for (int b = 0; b < NB; b++) srow += sqrtf(__uint_as_float(cdist[b * KC + j]));
      lsum += srow;
    }
  }
  red[t] = lsum; __syncthreads();
  for (int s = 512; s > 0; s >>= 1) { if (t < s) red[t] += red[t + s]; __syncthreads(); }
  float totloss = red[0]; __syncthreads();
  red[t] = ccount; __syncthreads();
  for (int s = 512; s > 0; s >>= 1) { if (t < s) red[t] += red[t + s]; __syncthreads(); }
  float cnt = red[0] * (float)NB;
  if (t == 0) {
    out[OUT_COMMIT] = commit / (float)(NROWS * CD);
    out[OUT_EMB] = totloss / fmaxf(cnt, 1.f);
  }
}

// --------- K4b: new_csum, centroids, new_cb (512 blocks x 256)
__global__ __launch_bounds__(256) void k4b_update(const float* __restrict__ cb,
                                                  const float* __restrict__ csum_in,
                                                  const float* __restrict__ ws,
                                                  float* __restrict__ out) {
  const int e = blockIdx.x * 256 + threadIdx.x;   // 0 .. NC*CD-1
  const int k = e >> 6;
  const unsigned* binc = (const unsigned*)(ws + WS_BINC);
  const float n = (ws + WS_N)[0];
  const float denom = n + (float)NC * 1e-5f;

  float ncsum = DECAY * csum_in[e] + (1.f - DECAY) * (ws + WS_SUMS)[e];
  out[OUT_CSUM + e] = ncsum;
  float smoothed = (out[OUT_CS + k] + 1e-5f) * n / denom;
  float cent = ncsum / smoothed;
  float v = (binc[k] != 0u) ? cent : cb[e];
  if (k == 0) v = 0.f;
  out[OUT_CB + e] = v;
}

extern "C" void kernel_launch(void* const* d_in, const int* in_sizes, int n_in,
                              void* d_out, int out_size, void* d_ws, size_t ws_size,
                              hipStream_t stream) {
  const float* x    = (const float*)d_in[0];
  const float* W    = (const float*)d_in[1];
  const float* b    = (const float*)d_in[2];
  const float* cb   = (const float*)d_in[3];
  const float* cs   = (const float*)d_in[4];
  const float* csum = (const float*)d_in[5];
  float* out = (float*)d_out;
  float* ws  = (float*)d_ws;

  const size_t need = ((size_t)WS_PART + (size_t)4 * NROWS * CD) * sizeof(float);
  const bool use_split = ws_size >= need;   // host-side, deterministic

  hipLaunchKernelGGL(k0_init, dim3(512), dim3(256), 0, stream, cb, ws);
  if (use_split) {
    hipLaunchKernelGGL(k1_split,  dim3(512),  dim3(256), 0, stream, x, W, ws);
    hipLaunchKernelGGL(k1_reduce, dim3(1024), dim3(256), 0, stream, b, ws);
    // MFMA path (scratch aliases PART region; no extra ws needed)
    hipLaunchKernelGGL(k_cvt,       dim3(576),       dim3(256), 0, stream, cb, ws);
    hipLaunchKernelGGL(k2m_dist,    dim3(2048),      dim3(64),  0, stream, ws);
    hipLaunchKernelGGL(k2m_rescore, dim3(64),        dim3(256), 0, stream, cb, ws, out);
    hipLaunchKernelGGL(k3m_scatter, dim3(K3_BLOCKS), dim3(256), 0, stream, cb, ws, out);
  } else {
    hipLaunchKernelGGL(k1_down,    dim3(256),       dim3(256), 0, stream, x, W, b, ws);
    hipLaunchKernelGGL(k2_dist,    dim3(512),       dim3(512), 0, stream, cb, ws);
    hipLaunchKernelGGL(k3_scatter, dim3(K3_BLOCKS), dim3(256), 0, stream, cb, ws, out);
  }
  hipLaunchKernelGGL(k4a_stats,  dim3(1),   dim3(1024), 0, stream, cs, ws, out);
  hipLaunchKernelGGL(k4b_update, dim3(512), dim3(256),  0, stream, cb, csum, ws, out);
}

// Round 13
// 213.403 us; speedup vs baseline: 1.1110x; 1.1110x over previous
//
#include <hip/hip_runtime.h>
#include <hip/hip_bf16.h>

// Problem constants
#define NROWS 16384   // 8*2048 tokens
#define DM    1024    // d_model
#define CD    64      // code depth
#define NC    2048    // num codes
#define KC    2047    // codes excluding index 0
#define NB    8       // batch
#define DECAY 0.99f
#define MARGIN 0.03f  // > 2*eps_bf16 (~0.016) for ||z||=||c||=1

#define K3_BLOCKS 512

// d_out layout (floats, concatenated in reference return order)
#define OUT_HARD   0
#define OUT_IDX    1048576
#define OUT_COMMIT 1064960
#define OUT_EMB    1064961
#define OUT_CB     1064962
#define OUT_CS     1196034
#define OUT_CSUM   1198082

// d_ws layout (float offsets)
#define WS_Z      0                          // 1048576 f
#define WS_CN2    1048576                    // 2048 f ([2047]=+INF pad)
#define WS_BINC   1050624                    // 2048 u32
#define WS_SUMS   1052672                    // 131072 f
#define WS_CDIST  1183744                    // 8*2047 u32
#define WS_COMMIT 1200120                    // 512 f per-block partials
#define WS_ZN2    1200632                    // 16384 f
#define WS_N      1217016                    // 1 f (+3 pad)
#define WS_PART   1298940                    // 4*16384*64 f split-K partials (k1 only)
// MFMA-path scratch ALIASES PART (dead after k1_reduce):
#define WS_ZB2    WS_PART                    // 16384*64 bf16 = 524288 f
#define WS_CBB2   (WS_PART + 524288)         // 2048*64 bf16 = 65536 f
#define WS_CNT    (WS_PART + 589824)         // 16384*4 u32 candidate counters
#define WS_CANDL  (WS_PART + 655360)         // 16384*4*32 u32 candidate lists
#define WS_IDXM2  (WS_PART + 2752512)        // 16384 i32 final idx
// legacy f32-path scratch (also aliases PART):
#define WS_BV     WS_PART                    // 4*16384 f  per-quarter best value
#define WS_BI     (WS_PART + 65536)          // 4*16384 i32 per-quarter best idx (+1)

#define F32_INF_BITS 0x7F800000u

typedef __attribute__((ext_vector_type(8))) short short8;
typedef __attribute__((ext_vector_type(4))) float f32x4;

__device__ inline unsigned short f2bf(float f) {
  __hip_bfloat16 h = __float2bfloat16(f);   // RNE
  return *reinterpret_cast<unsigned short*>(&h);
}

// ---------------------------------------------------------------- K0: init
__global__ __launch_bounds__(256) void k0_init(const float* __restrict__ cb,
                                               float* __restrict__ ws) {
  int i = blockIdx.x * 256 + threadIdx.x;
  if (i < NC * CD) (ws + WS_SUMS)[i] = 0.0f;
  if (i < NC) {
    ((unsigned*)(ws + WS_BINC))[i] = 0u;
    float cn2;
    if (i < KC) {
      const float* c = cb + (size_t)(i + 1) * CD;
      float s0 = 0.f, s1 = 0.f;
      #pragma unroll
      for (int d = 0; d < CD; d += 2) { s0 = fmaf(c[d], c[d], s0); s1 = fmaf(c[d+1], c[d+1], s1); }
      cn2 = s0 + s1;
    } else {
      cn2 = __uint_as_float(F32_INF_BITS);
    }
    (ws + WS_CN2)[i] = cn2;
  }
  if (i < NB * KC) ((unsigned*)(ws + WS_CDIST))[i] = F32_INF_BITS;
}

// ------------- K1 (split-K): partial[kslice] = x[:,ks*256:+256] @ W^T slice
// 256 thr/block, 8 rows x 4 cols/thread, BK=64, grid 512 (proven R11).
__global__ __launch_bounds__(256) void k1_split(const float* __restrict__ x,
                                                const float* __restrict__ W,
                                                float* __restrict__ ws) {
  __shared__ float xs[64][132];   // [k][row'] swizzled
  __shared__ float wls[64][68];   // [k][col]
  const int t = threadIdx.x;             // 0..255
  const int ks = blockIdx.x & 3;
  const int row0 = (blockIdx.x >> 2) * 128;
  const int kbase = ks * 256;
  const int tx = t & 15, ty = t >> 4;    // tx: 16 col-groups(x4), ty: 16 row-groups(x8)
  const int sseg = t & 15, srow = t >> 4;

  float4 px[8], pw[4];
  auto ld = [&](int kt) {
    const int kk = kbase + kt * 64;
    #pragma unroll
    for (int it = 0; it < 8; ++it)
      px[it] = *(const float4*)(x + (size_t)(row0 + srow + 16 * it) * DM + kk + sseg * 4);
    #pragma unroll
    for (int it = 0; it < 4; ++it)
      pw[it] = *(const float4*)(W + (size_t)(srow + 16 * it) * DM + kk + sseg * 4);
  };
  ld(0);

  float acc[8][4];
  #pragma unroll
  for (int i = 0; i < 8; i++)
    #pragma unroll
    for (int j = 0; j < 4; j++) acc[i][j] = 0.f;

  for (int kt = 0; kt < 4; ++kt) {
    __syncthreads();
    const int sg4 = sseg * 4;
    #pragma unroll
    for (int it = 0; it < 8; ++it) {
      const int cpos = (srow + 16 * it) ^ ((sseg & 3) << 3);
      xs[sg4 + 0][cpos] = px[it].x; xs[sg4 + 1][cpos] = px[it].y;
      xs[sg4 + 2][cpos] = px[it].z; xs[sg4 + 3][cpos] = px[it].w;
    }
    #pragma unroll
    for (int it = 0; it < 4; ++it) {
      const int wcol = srow + 16 * it;
      wls[sg4 + 0][wcol] = pw[it].x; wls[sg4 + 1][wcol] = pw[it].y;
      wls[sg4 + 2][wcol] = pw[it].z; wls[sg4 + 3][wcol] = pw[it].w;
    }
    __syncthreads();
    if (kt < 3) ld(kt + 1);

    #pragma unroll 8
    for (int dl = 0; dl < 64; ++dl) {
      const int xcol = (ty * 8) ^ (((dl >> 2) & 3) << 3);
      float4 xv0 = *(const float4*)(&xs[dl][xcol]);
      float4 xv1 = *(const float4*)(&xs[dl][xcol + 4]);
      float4 wv  = *(const float4*)(&wls[dl][tx * 4]);
      float xz[8] = {xv0.x, xv0.y, xv0.z, xv0.w, xv1.x, xv1.y, xv1.z, xv1.w};
      float wc[4] = {wv.x, wv.y, wv.z, wv.w};
      #pragma unroll
      for (int i = 0; i < 8; i++)
        #pragma unroll
        for (int j = 0; j < 4; j++)
          acc[i][j] = fmaf(xz[i], wc[j], acc[i][j]);
    }
  }

  float* part = ws + WS_PART + (size_t)ks * NROWS * CD;
  #pragma unroll
  for (int i = 0; i < 8; i++) {
    const int row = row0 + ty * 8 + i;
    float4 v; v.x = acc[i][0]; v.y = acc[i][1]; v.z = acc[i][2]; v.w = acc[i][3];
    *(float4*)(part + (size_t)row * CD + tx * 4) = v;
  }
}

// ------------- K1r: sum 4 partials + bias, row-normalize, write z/zn2
__global__ __launch_bounds__(256) void k1_reduce(const float* __restrict__ bdown,
                                                 float* __restrict__ ws) {
  const int t = threadIdx.x;
  const int tx = t & 15, ty = t >> 4;
  const int row = blockIdx.x * 16 + ty;
  const float* part = ws + WS_PART;
  const size_t off = (size_t)row * CD + tx * 4;

  float4 v0 = *(const float4*)(part + off);
  float4 v1 = *(const float4*)(part + (size_t)1 * NROWS * CD + off);
  float4 v2 = *(const float4*)(part + (size_t)2 * NROWS * CD + off);
  float4 v3 = *(const float4*)(part + (size_t)3 * NROWS * CD + off);
  float4 b  = *(const float4*)(bdown + tx * 4);
  float4 v;
  v.x = (v0.x + v1.x) + (v2.x + v3.x) + b.x;
  v.y = (v0.y + v1.y) + (v2.y + v3.y) + b.y;
  v.z = (v0.z + v1.z) + (v2.z + v3.z) + b.z;
  v.w = (v0.w + v1.w) + (v2.w + v3.w) + b.w;

  float ss = v.x * v.x + v.y * v.y + v.z * v.z + v.w * v.w;
  #pragma unroll
  for (int m = 1; m < 16; m <<= 1) ss += __shfl_xor(ss, m, 64);
  float inv = 1.0f / sqrtf(ss);   // uniform per-row scale: argmin-safe
  float4 zv; zv.x = v.x * inv; zv.y = v.y * inv; zv.z = v.z * inv; zv.w = v.w * inv;
  *(float4*)(ws + WS_Z + off) = zv;
  if (tx == 0) (ws + WS_ZN2)[row] = ss * inv * inv;
}

// ------------- K1 legacy (used only if ws too small for split-K partials)
__global__ __launch_bounds__(256) void k1_down(const float* __restrict__ x,
                                               const float* __restrict__ W,
                                               const float* __restrict__ bdown,
                                               float* __restrict__ ws) {
  __shared__ float xs[64][68];
  __shared__ float wls[64][68];
  const int t = threadIdx.x;
  const int row0 = blockIdx.x * 64;
  const int tx = t & 15, ty = t >> 4;

  int pr[4], pseg[4];
  #pragma unroll
  for (int it = 0; it < 4; ++it) { int c = t + it * 256; pr[it] = c >> 4; pseg[it] = c & 15; }

  float4 px[4], pw[4];
  #pragma unroll
  for (int it = 0; it < 4; ++it) {
    px[it] = *(const float4*)(x + (size_t)(row0 + pr[it]) * DM + pseg[it] * 4);
    pw[it] = *(const float4*)(W + (size_t)pr[it] * DM + pseg[it] * 4);
  }

  float acc[4][4];
  #pragma unroll
  for (int i = 0; i < 4; i++)
    #pragma unroll
    for (int j = 0; j < 4; j++) acc[i][j] = 0.f;

  for (int kt = 0; kt < 16; ++kt) {
    __syncthreads();
    #pragma unroll
    for (int it = 0; it < 4; ++it) {
      *(float4*)(&xs[pr[it]][pseg[it] * 4]) = px[it];
      *(float4*)(&wls[pr[it]][pseg[it] * 4]) = pw[it];
    }
    __syncthreads();
    if (kt < 15) {
      const int k0 = (kt + 1) * 64;
      #pragma unroll
      for (int it = 0; it < 4; ++it) {
        px[it] = *(const float4*)(x + (size_t)(row0 + pr[it]) * DM + k0 + pseg[it] * 4);
        pw[it] = *(const float4*)(W + (size_t)pr[it] * DM + k0 + pseg[it] * 4);
      }
    }
    #pragma unroll 4
    for (int k = 0; k < 64; k += 4) {
      float4 xv[4], wv[4];
      #pragma unroll
      for (int i = 0; i < 4; i++) xv[i] = *(const float4*)(&xs[ty * 4 + i][k]);
      #pragma unroll
      for (int j = 0; j < 4; j++) wv[j] = *(const float4*)(&wls[tx * 4 + j][k]);
      #pragma unroll
      for (int i = 0; i < 4; i++)
        #pragma unroll
        for (int j = 0; j < 4; j++)
          acc[i][j] = fmaf(xv[i].x, wv[j].x, fmaf(xv[i].y, wv[j].y,
                      fmaf(xv[i].z, wv[j].z, fmaf(xv[i].w, wv[j].w, acc[i][j]))));
    }
  }

  #pragma unroll
  for (int j = 0; j < 4; j++) {
    float bj = bdown[tx * 4 + j];
    #pragma unroll
    for (int i = 0; i < 4; i++) acc[i][j] += bj;
  }

  float* z = ws + WS_Z;
  float* zn2 = ws + WS_ZN2;
  #pragma unroll
  for (int i = 0; i < 4; i++) {
    float ss = acc[i][0] * acc[i][0] + acc[i][1] * acc[i][1] +
               acc[i][2] * acc[i][2] + acc[i][3] * acc[i][3];
    #pragma unroll
    for (int m = 1; m < 16; m <<= 1) ss += __shfl_xor(ss, m, 64);
    float inv = 1.0f / sqrtf(ss);
    float4 zv;
    zv.x = acc[i][0] * inv; zv.y = acc[i][1] * inv;
    zv.z = acc[i][2] * inv; zv.w = acc[i][3] * inv;
    int row = row0 + ty * 4 + i;
    *(float4*)(z + (size_t)row * CD + tx * 4) = zv;
    if (tx == 0) zn2[row] = ss * inv * inv;
  }
}

// ------------- K_CVT: z -> bf16 zb; cb -> bf16 cbb (pad 0); zero counters.
__global__ __launch_bounds__(256) void k_cvt(const float* __restrict__ cb,
                                             float* __restrict__ ws) {
  const int i = blockIdx.x * 256 + threadIdx.x;
  unsigned short u[8];
  if (i < NROWS * CD / 8) {
    const float* src = ws + WS_Z + (size_t)i * 8;
    #pragma unroll
    for (int e = 0; e < 8; ++e) u[e] = f2bf(src[e]);
    *(short8*)((unsigned short*)(ws + WS_ZB2) + (size_t)i * 8) = *(short8*)u;
  } else if (i < NROWS * CD / 8 + NC * CD / 8) {
    const int j = i - NROWS * CD / 8;
    #pragma unroll
    for (int e = 0; e < 8; ++e) {
      const int f = j * 8 + e;                    // cbb flat idx: code*64+d
      u[e] = (f < KC * CD) ? f2bf(cb[f + CD]) : (unsigned short)0;
    }
    *(short8*)((unsigned short*)(ws + WS_CBB2) + (size_t)j * 8) = *(short8*)u;
  } else if (i < NROWS * CD / 8 + NC * CD / 8 + NROWS * 4) {
    ((unsigned*)(ws + WS_CNT))[i - (NROWS * CD / 8 + NC * CD / 8)] = 0u;
  }
}

// ---- K2M v2: bf16 MFMA two-pass. 512 blocks x 512 thr (8 waves):
// wave = (rowgroup pair-half, code quarter). Pass 1: row-min + cdist colmin.
// Pass 2: re-run MFMAs, append codes with s <= rowmin+MARGIN to per-(row,
// quarter) candidate lists (>=1 per quarter: the quarter-min qualifies).
// Frag mapping identical to validated R12 kernel.
__global__ __launch_bounds__(512) void k2m_dist(float* __restrict__ ws) {
  const int t = threadIdx.x;
  const int l = t & 63;
  const int wv = t >> 6;                     // 0..7
  const int rg = blockIdx.x * 2 + (wv >> 2); // rowgroup 0..1023
  const int wq = wv & 3;                     // code quarter
  const int row0 = rg * 16;
  const int batch = row0 >> 11;
  const unsigned short* zb = (const unsigned short*)(ws + WS_ZB2);
  const unsigned short* cbb = (const unsigned short*)(ws + WS_CBB2);
  const float* cn2p = ws + WS_CN2;
  unsigned* cdist = (unsigned*)(ws + WS_CDIST) + (size_t)batch * KC;
  unsigned* cntp = (unsigned*)(ws + WS_CNT);
  unsigned* candl = (unsigned*)(ws + WS_CANDL);

  const int col = l & 15, kb = l >> 4;
  const size_t za = (size_t)(row0 + col) * CD + kb * 8;
  const short8 A0 = *(const short8*)(zb + za);
  const short8 A1 = *(const short8*)(zb + za + 32);

  float zn2q[4];
  #pragma unroll
  for (int q = 0; q < 4; ++q) zn2q[q] = (ws + WS_ZN2)[row0 + kb * 4 + q];

  const int tile0 = wq * 32;
  float rmin[4];
  #pragma unroll
  for (int q = 0; q < 4; ++q) rmin[q] = __uint_as_float(F32_INF_BITS);

  short8 B0, B1; float c2;
  {
    const size_t ca = (size_t)(tile0 * 16 + col) * CD + kb * 8;
    B0 = *(const short8*)(cbb + ca);
    B1 = *(const short8*)(cbb + ca + 32);
    c2 = cn2p[tile0 * 16 + col];
  }

  // ---- pass 1: per-row min + per-code column-min (cdist)
  for (int tt = 0; tt < 32; ++tt) {
    const int tile = tile0 + tt;
    short8 nB0, nB1; float nc2 = 0.f;
    if (tt < 31) {
      const size_t ca = (size_t)((tile + 1) * 16 + col) * CD + kb * 8;
      nB0 = *(const short8*)(cbb + ca);
      nB1 = *(const short8*)(cbb + ca + 32);
      nc2 = cn2p[(tile + 1) * 16 + col];
    }
    f32x4 acc = {0.f, 0.f, 0.f, 0.f};
    acc = __builtin_amdgcn_mfma_f32_16x16x32_bf16(A0, B0, acc, 0, 0, 0);
    acc = __builtin_amdgcn_mfma_f32_16x16x32_bf16(A1, B1, acc, 0, 0, 0);
    const int code = tile * 16 + col;
    float cmin = __uint_as_float(F32_INF_BITS);
    #pragma unroll
    for (int q = 0; q < 4; ++q) {
      const float s = fmaf(-2.f, acc[q], c2);
      rmin[q] = fminf(rmin[q], s);
      float v = zn2q[q] + s;
      v = v < 0.f ? 0.f : v;        // clamp(d2,0): monotone under sqrt/min
      cmin = fminf(cmin, v);
    }
    cmin = fminf(cmin, __shfl_xor(cmin, 16, 64));
    cmin = fminf(cmin, __shfl_xor(cmin, 32, 64));
    if (l < 16 && code < KC) atomicMin(&cdist[code], __float_as_uint(cmin));
    B0 = nB0; B1 = nB1; c2 = nc2;
  }

  // reduce rmin across the 16 cols (masks 1..8 stay within each kb-group)
  #pragma unroll
  for (int m = 1; m <= 8; m <<= 1)
    #pragma unroll
    for (int q = 0; q < 4; ++q)
      rmin[q] = fminf(rmin[q], __shfl_xor(rmin[q], m, 64));
  float thrq[4];
  #pragma unroll
  for (int q = 0; q < 4; ++q) thrq[q] = rmin[q] + MARGIN;

  // ---- pass 2: collect candidates within margin
  {
    const size_t ca = (size_t)(tile0 * 16 + col) * CD + kb * 8;
    B0 = *(const short8*)(cbb + ca);
    B1 = *(const short8*)(cbb + ca + 32);
    c2 = cn2p[tile0 * 16 + col];
  }
  for (int tt = 0; tt < 32; ++tt) {
    const int tile = tile0 + tt;
    short8 nB0, nB1; float nc2 = 0.f;
    if (tt < 31) {
      const size_t ca = (size_t)((tile + 1) * 16 + col) * CD + kb * 8;
      nB0 = *(const short8*)(cbb + ca);
      nB1 = *(const short8*)(cbb + ca + 32);
      nc2 = cn2p[(tile + 1) * 16 + col];
    }
    f32x4 acc = {0.f, 0.f, 0.f, 0.f};
    acc = __builtin_amdgcn_mfma_f32_16x16x32_bf16(A0, B0, acc, 0, 0, 0);
    acc = __builtin_amdgcn_mfma_f32_16x16x32_bf16(A1, B1, acc, 0, 0, 0);
    const int code = tile * 16 + col;
    if (code < KC) {
      #pragma unroll
      for (int q = 0; q < 4; ++q) {
        const float s = fmaf(-2.f, acc[q], c2);
        if (s <= thrq[q]) {
          const int row = row0 + kb * 4 + q;
          const unsigned slot = atomicAdd(&cntp[row * 4 + wq], 1u);
          if (slot < 32u) candl[(size_t)(row * 4 + wq) * 32 + slot] = (unsigned)code;
        }
      }
    }
    B0 = nB0; B1 = nB1; c2 = nc2;
  }
}

// ---- K2M-R v2: wave-per-row exact f32 rescore (lane-per-candidate).
// f32 chain = d-ascending fmaf, identical to the 12-round-proven f32 path;
// argmin tie-break = lowest code = first occurrence.
__global__ __launch_bounds__(512) void k2m_rescore(const float* __restrict__ cb,
                                                   float* __restrict__ ws,
                                                   float* __restrict__ out) {
  const int t = threadIdx.x;
  const int l = t & 63;
  const int row = blockIdx.x * 8 + (t >> 6);   // grid 2048
  const unsigned* cntp = (const unsigned*)(ws + WS_CNT);
  const unsigned* candl = (const unsigned*)(ws + WS_CANDL);
  const float* z = ws + WS_Z + (size_t)row * CD;
  const float* cn2p = ws + WS_CN2;

  float bv = __uint_as_float(F32_INF_BITS);
  int bi = 0x7FFFFFFF;
  #pragma unroll
  for (int q = 0; q < 4; ++q) {
    const unsigned cnt = min(cntp[row * 4 + q], 32u);
    if ((unsigned)l < cnt) {
      const int code = (int)candl[(size_t)(row * 4 + q) * 32 + l];
      const float* c = cb + (size_t)(code + 1) * CD;
      float dot = 0.f;
      #pragma unroll
      for (int d = 0; d < 64; ++d) dot = fmaf(z[d], c[d], dot);
      const float sc = fmaf(-2.f, dot, cn2p[code]);
      if (sc < bv || (sc == bv && code < bi)) { bv = sc; bi = code; }
    }
  }
  #pragma unroll
  for (int m = 1; m < 64; m <<= 1) {
    const float ov = __shfl_xor(bv, m, 64);
    const int oi = __shfl_xor(bi, m, 64);
    if (ov < bv || (ov == bv && oi < bi)) { bv = ov; bi = oi; }
  }
  if (l == 0) {
    const int idx = bi + 1;
    ((int*)(ws + WS_IDXM2))[row] = idx;
    out[OUT_IDX + row] = (float)idx;
  }
}

// ---- K2 legacy f32 (fallback path; proven 70.7us)
__global__ __launch_bounds__(512) void k2_dist(const float* __restrict__ cbp,
                                               float* __restrict__ ws) {
  __shared__ float zT[64][132];
  __shared__ float cT[64][132];
  __shared__ float cn2s[128];
  __shared__ float zn2s[128];
  __shared__ unsigned colmin[128];

  const int t = threadIdx.x;
  const int gq = blockIdx.x & 3;
  const int rt = blockIdx.x >> 2;
  const int row0 = rt << 7;
  const int batch = rt >> 4;
  const int tx = t & 31, ty = t >> 5;
  const float* z = ws + WS_Z;
  const float* cn2p = ws + WS_CN2;
  unsigned* cdist = (unsigned*)(ws + WS_CDIST) + (size_t)batch * KC;

  if (t < 128) zn2s[t] = (ws + WS_ZN2)[row0 + t];

  {
    const int sr = t >> 2, sp = t & 3;
    float4 v[4];
    #pragma unroll
    for (int it = 0; it < 4; ++it)
      v[it] = *(const float4*)(z + (size_t)(row0 + sr) * CD + (sp + 4 * it) * 4);
    #pragma unroll
    for (int it = 0; it < 4; ++it) {
      const int sg4 = (sp + 4 * it) * 4;
      zT[sg4 + 0][sr] = v[it].x; zT[sg4 + 1][sr] = v[it].y;
      zT[sg4 + 2][sr] = v[it].z; zT[sg4 + 3][sr] = v[it].w;
    }
  }

  const int cr = t >> 2, cp = t & 3;
  const int ccol = cr ^ (((cr >> 5) & 3) << 2);
  float4 pc[4];
  auto ldc = [&](int lt) {
    const int code = gq * 512 + lt * 128 + cr;
    #pragma unroll
    for (int it = 0; it < 4; ++it)
      pc[it] = (code < KC) ? *(const float4*)(cbp + (size_t)(code + 1) * CD + (cp + 4 * it) * 4)
                           : make_float4(0.f, 0.f, 0.f, 0.f);
  };
  ldc(0);

  float bestv[8];
  int besti[8];
  #pragma unroll
  for (int i = 0; i < 8; i++) { bestv[i] = __uint_as_float(F32_INF_BITS); besti[i] = 0; }

  const int ccol0 = (tx * 4) ^ (((tx >> 3) & 3) << 2);

  for (int lt = 0; lt < 4; ++lt) {
    __syncthreads();
    #pragma unroll
    for (int it = 0; it < 4; ++it) {
      const int sg4 = (cp + 4 * it) * 4;
      cT[sg4 + 0][ccol] = pc[it].x; cT[sg4 + 1][ccol] = pc[it].y;
      cT[sg4 + 2][ccol] = pc[it].z; cT[sg4 + 3][ccol] = pc[it].w;
    }
    if (t < 128) {
      cn2s[t] = cn2p[gq * 512 + lt * 128 + t];
      colmin[t] = F32_INF_BITS;
    }
    __syncthreads();
    if (lt < 3) ldc(lt + 1);

    float acc[8][4];
    #pragma unroll
    for (int i = 0; i < 8; i++)
      #pragma unroll
      for (int j = 0; j < 4; j++) acc[i][j] = 0.f;

    #pragma unroll 8
    for (int d = 0; d < 64; ++d) {
      float4 za = *(const float4*)(&zT[d][ty * 8]);
      float4 zb = *(const float4*)(&zT[d][ty * 8 + 4]);
      float4 cv = *(const float4*)(&cT[d][ccol0]);
      float zz[8] = {za.x, za.y, za.z, za.w, zb.x, zb.y, zb.z, zb.w};
      float cc[4] = {cv.x, cv.y, cv.z, cv.w};
      #pragma unroll
      for (int i = 0; i < 8; i++)
        #pragma unroll
        for (int j = 0; j < 4; j++)
          acc[i][j] = fmaf(zz[i], cc[j], acc[i][j]);
    }

    const int jbase = gq * 512 + lt * 128;
    #pragma unroll
    for (int jl = 0; jl < 4; ++jl) {
      const int jloc = tx * 4 + jl;
      const int jg = jbase + jloc;
      const float c2 = cn2s[jloc];
      float colv = __uint_as_float(F32_INF_BITS);
      #pragma unroll
      for (int i = 0; i < 8; ++i) {
        float s = fmaf(-2.f, acc[i][jl], c2);
        if (s < bestv[i]) { bestv[i] = s; besti[i] = jg; }
        float v = zn2s[ty * 8 + i] + s;
        v = v < 0.f ? 0.f : v;
        colv = v < colv ? v : colv;
      }
      colv = fminf(colv, __shfl_xor(colv, 32, 64));
      if ((t & 32) == 0) atomicMin(&colmin[jloc], __float_as_uint(colv));
    }
    __syncthreads();
    if (t < 128) {
      const int jg2 = jbase + t;
      if (jg2 < KC) atomicMin(&cdist[jg2], colmin[t]);
    }
  }

  #pragma unroll
  for (int m = 1; m <= 16; m <<= 1) {
    #pragma unroll
    for (int i = 0; i < 8; i++) {
      float ov = __shfl_xor(bestv[i], m, 64);
      int oi = __shfl_xor(besti[i], m, 64);
      if (ov < bestv[i] || (ov == bestv[i] && oi < besti[i])) { bestv[i] = ov; besti[i] = oi; }
    }
  }
  if (tx == 0) {
    #pragma unroll
    for (int i = 0; i < 8; i++) {
      const int row = row0 + ty * 8 + i;
      (ws + WS_BV)[(size_t)gq * NROWS + row] = bestv[i];
      ((int*)(ws + WS_BI))[(size_t)gq * NROWS + row] = besti[i] + 1;
    }
  }
}

// ------- K3M: gather + commitment + scatter, idx precomputed (MFMA path)
__global__ __launch_bounds__(256) void k3m_scatter(const float* __restrict__ cb,
                                                   float* __restrict__ ws,
                                                   float* __restrict__ out) {
  const int t = threadIdx.x;
  const int lane = t & 63;
  const int w = t >> 6;
  const int rowbase = blockIdx.x * 32 + w * 8;
  const float* z = ws + WS_Z;

  const int myidx = ((const int*)(ws + WS_IDXM2))[rowbase + (lane & 7)];

  float sq = 0.f;
  #pragma unroll
  for (int r = 0; r < 8; ++r) {
    const int idx = __shfl(myidx, r, 8);
    const int row = rowbase + r;
    const float c = cb[(size_t)idx * CD + lane];
    const float zv = z[(size_t)row * CD + lane];
    out[OUT_HARD + (size_t)row * CD + lane] = zv + (c - zv);
    const float d = c - zv;
    sq = fmaf(d, d, sq);
    atomicAdd(ws + WS_SUMS + (size_t)idx * CD + lane, zv);
    if (lane == 0) atomicAdd((unsigned*)(ws + WS_BINC) + idx, 1u);
  }

  __shared__ float red[4];
  #pragma unroll
  for (int m = 1; m < 64; m <<= 1) sq += __shfl_xor(sq, m, 64);
  if (lane == 0) red[w] = sq;
  __syncthreads();
  if (t == 0) (ws + WS_COMMIT)[blockIdx.x] = red[0] + red[1] + red[2] + red[3];
}

// ------- K3 legacy: inline quarter-argmin merge + gather + scatter
__global__ __launch_bounds__(256) void k3_scatter(const float* __restrict__ cb,
                                                  float* __restrict__ ws,
                                                  float* __restrict__ out) {
  const int t = threadIdx.x;
  const int lane = t & 63;
  const int w = t >> 6;
  const int rowbase = blockIdx.x * 32 + w * 8;
  const float* z = ws + WS_Z;

  const int myrow = rowbase + (lane & 7);
  float bv = (ws + WS_BV)[myrow];
  int myidx = ((const int*)(ws + WS_BI))[myrow];
  #pragma unroll
  for (int g2 = 1; g2 < 4; ++g2) {
    float v = (ws + WS_BV)[(size_t)g2 * NROWS + myrow];
    int i2 = ((const int*)(ws + WS_BI))[(size_t)g2 * NROWS + myrow];
    if (v < bv) { bv = v; myidx = i2; }
  }
  if (lane < 8) out[OUT_IDX + myrow] = (float)myidx;

  float sq = 0.f;
  #pragma unroll
  for (int r = 0; r < 8; ++r) {
    const int idx = __shfl(myidx, r, 8);
    const int row = rowbase + r;
    const float c = cb[(size_t)idx * CD + lane];
    const float zv = z[(size_t)row * CD + lane];
    out[OUT_HARD + (size_t)row * CD + lane] = zv + (c - zv);
    const float d = c - zv;
    sq = fmaf(d, d, sq);
    atomicAdd(ws + WS_SUMS + (size_t)idx * CD + lane, zv);
    if (lane == 0) atomicAdd((unsigned*)(ws + WS_BINC) + idx, 1u);
  }

  __shared__ float red[4];
  #pragma unroll
  for (int m = 1; m < 64; m <<= 1) sq += __shfl_xor(sq, m, 64);
  if (lane == 0) red[w] = sq;
  __syncthreads();
  if (t == 0) (ws + WS_COMMIT)[blockIdx.x] = red[0] + red[1] + red[2] + red[3];
}

// --------- K4a: new_cs + n + losses (single block, small data only)
__global__ __launch_bounds__(1024) void k4a_stats(const float* __restrict__ cs_in,
                                                  float* __restrict__ ws,
                                                  float* __restrict__ out) {
  __shared__ float red[1024];
  const int t = threadIdx.x;
  const unsigned* binc = (const unsigned*)(ws + WS_BINC);

  float npart = 0.f;
  #pragma unroll
  for (int i = t; i < NC; i += 1024) {
    float nc = DECAY * cs_in[i] + (1.f - DECAY) * (float)binc[i];
    out[OUT_CS + i] = nc;
    npart += nc;
  }
  red[t] = npart; __syncthreads();
  for (int s = 512; s > 0; s >>= 1) { if (t < s) red[t] += red[t + s]; __syncthreads(); }
  if (t == 0) (ws + WS_N)[0] = red[0];
  __syncthreads();

  float cpart = 0.f;
  for (int j = t; j < K3_BLOCKS; j += 1024) cpart += (ws + WS_COMMIT)[j];
  red[t] = cpart; __syncthreads();
  for (int s = 512; s > 0; s >>= 1) { if (t < s) red[t] += red[t + s]; __syncthreads(); }
  float commit = red[0]; __syncthreads();

  const unsigned* cdist = (const unsigned*)(ws + WS_CDIST);
  float lsum = 0.f, ccount = 0.f;
  for (int j = t; j < KC; j += 1024) {
    if (binc[j + 1] == 0u) {
      ccount += 1.f;
      float srow = 0.f;
      #pragma unroll
      for (int b = 0; b < NB; b++) srow += sqrtf(__uint_as_float(cdist[b * KC + j]));
      lsum += srow;
    }
  }
  red[t] = lsum; __syncthreads();
  for (int s = 512; s > 0; s >>= 1) { if (t < s) red[t] += red[t + s]; __syncthreads(); }
  float totloss = red[0]; __syncthreads();
  red[t] = ccount; __syncthreads();
  for (int s = 512; s > 0; s >>= 1) { if (t < s) red[t] += red[t + s]; __syncthreads(); }
  float cnt = red[0] * (float)NB;
  if (t == 0) {
    out[OUT_COMMIT] = commit / (float)(NROWS * CD);
    out[OUT_EMB] = totloss / fmaxf(cnt, 1.f);
  }
}

// --------- K4b: new_csum, centroids, new_cb (512 blocks x 256)
__global__ __launch_bounds__(256) void k4b_update(const float* __restrict__ cb,
                                                  const float* __restrict__ csum_in,
                                                  const float* __restrict__ ws,
                                                  float* __restrict__ out) {
  const int e = blockIdx.x * 256 + threadIdx.x;   // 0 .. NC*CD-1
  const int k = e >> 6;
  const unsigned* binc = (const unsigned*)(ws + WS_BINC);
  const float n = (ws + WS_N)[0];
  const float denom = n + (float)NC * 1e-5f;

  float ncsum = DECAY * csum_in[e] + (1.f - DECAY) * (ws + WS_SUMS)[e];
  out[OUT_CSUM + e] = ncsum;
  float smoothed = (out[OUT_CS + k] + 1e-5f) * n / denom;
  float cent = ncsum / smoothed;
  float v = (binc[k] != 0u) ? cent : cb[e];
  if (k == 0) v = 0.f;
  out[OUT_CB + e] = v;
}

extern "C" void kernel_launch(void* const* d_in, const int* in_sizes, int n_in,
                              void* d_out, int out_size, void* d_ws, size_t ws_size,
                              hipStream_t stream) {
  const float* x    = (const float*)d_in[0];
  const float* W    = (const float*)d_in[1];
  const float* b    = (const float*)d_in[2];
  const float* cb   = (const float*)d_in[3];
  const float* cs   = (const float*)d_in[4];
  const float* csum = (const float*)d_in[5];
  float* out = (float*)d_out;
  float* ws  = (float*)d_ws;

  const size_t need = ((size_t)WS_PART + (size_t)4 * NROWS * CD) * sizeof(float);
  const bool use_split = ws_size >= need;   // host-side, deterministic

  hipLaunchKernelGGL(k0_init, dim3(512), dim3(256), 0, stream, cb, ws);
  if (use_split) {
    hipLaunchKernelGGL(k1_split,  dim3(512),  dim3(256), 0, stream, x, W, ws);
    hipLaunchKernelGGL(k1_reduce, dim3(1024), dim3(256), 0, stream, b, ws);
    // MFMA path (scratch aliases PART region)
    hipLaunchKernelGGL(k_cvt,       dim3(832),       dim3(256), 0, stream, cb, ws);
    hipLaunchKernelGGL(k2m_dist,    dim3(512),       dim3(512), 0, stream, ws);
    hipLaunchKernelGGL(k2m_rescore, dim3(2048),      dim3(512), 0, stream, cb, ws, out);
    hipLaunchKernelGGL(k3m_scatter, dim3(K3_BLOCKS), dim3(256), 0, stream, cb, ws, out);
  } else {
    hipLaunchKernelGGL(k1_down,    dim3(256),       dim3(256), 0, stream, x, W, b, ws);
    hipLaunchKernelGGL(k2_dist,    dim3(512),       dim3(512), 0, stream, cb, ws);
    hipLaunchKernelGGL(k3_scatter, dim3(K3_BLOCKS), dim3(256), 0, stream, cb, ws, out);
  }
  hipLaunchKernelGGL(k4a_stats,  dim3(1),   dim3(1024), 0, stream, cs, ws, out);
  hipLaunchKernelGGL(k4b_update, dim3(512), dim3(256),  0, stream, cb, csum, ws, out);
}

// Round 14
// 186.859 us; speedup vs baseline: 1.2689x; 1.1421x over previous
//
#include <hip/hip_runtime.h>
#include <hip/hip_bf16.h>

// Problem constants
#define NROWS 16384   // 8*2048 tokens
#define DM    1024    // d_model
#define CD    64      // code depth
#define NC    2048    // num codes
#define KC    2047    // codes excluding index 0
#define NB    8       // batch
#define DECAY 0.99f
#define MARGIN 0.03f  // > 2*eps_bf16 (~0.016) for ||z||=||c||=1

#define K3_BLOCKS 512

// d_out layout (floats, concatenated in reference return order)
#define OUT_HARD   0
#define OUT_IDX    1048576
#define OUT_COMMIT 1064960
#define OUT_EMB    1064961
#define OUT_CB     1064962
#define OUT_CS     1196034
#define OUT_CSUM   1198082

// d_ws layout (float offsets)
#define WS_Z      0                          // 1048576 f
#define WS_CN2    1048576                    // 2048 f ([2047]=+INF pad)
#define WS_BINC   1050624                    // 2048 u32
#define WS_SUMS   1052672                    // 131072 f
#define WS_CDIST  1183744                    // 8*2047 u32
#define WS_COMMIT 1200120                    // 512 f per-block partials
#define WS_ZN2    1200632                    // 16384 f
#define WS_N      1217016                    // 1 f (+3 pad)
#define WS_PART   1298940                    // 4*16384*64 f split-K partials (k1 only)
// MFMA-path scratch ALIASES PART (dead after k1_reduce):
#define WS_ZB2    WS_PART                    // 16384*64 bf16 = 524288 f
#define WS_CBB2   (WS_PART + 524288)         // 2048*64 bf16 = 65536 f
#define WS_CNT    (WS_PART + 589824)         // 16384*4 u32 candidate counters
#define WS_CANDL  (WS_PART + 655360)         // 16384*4*32 u32 candidate lists
#define WS_IDXM2  (WS_PART + 2752512)        // 16384 i32 final idx
// legacy f32-path scratch (also aliases PART):
#define WS_BV     WS_PART                    // 4*16384 f  per-quarter best value
#define WS_BI     (WS_PART + 65536)          // 4*16384 i32 per-quarter best idx (+1)

#define F32_INF_BITS 0x7F800000u

typedef __attribute__((ext_vector_type(8))) short short8;
typedef __attribute__((ext_vector_type(4))) float f32x4;

__device__ inline unsigned short f2bf(float f) {
  __hip_bfloat16 h = __float2bfloat16(f);   // RNE
  return *reinterpret_cast<unsigned short*>(&h);
}

// ---------------------------------------------------------------- K0: init
__global__ __launch_bounds__(256) void k0_init(const float* __restrict__ cb,
                                               float* __restrict__ ws) {
  int i = blockIdx.x * 256 + threadIdx.x;
  if (i < NC * CD) (ws + WS_SUMS)[i] = 0.0f;
  if (i < NC) {
    ((unsigned*)(ws + WS_BINC))[i] = 0u;
    float cn2;
    if (i < KC) {
      const float* c = cb + (size_t)(i + 1) * CD;
      float s0 = 0.f, s1 = 0.f;
      #pragma unroll
      for (int d = 0; d < CD; d += 2) { s0 = fmaf(c[d], c[d], s0); s1 = fmaf(c[d+1], c[d+1], s1); }
      cn2 = s0 + s1;
    } else {
      cn2 = __uint_as_float(F32_INF_BITS);
    }
    (ws + WS_CN2)[i] = cn2;
  }
  if (i < NB * KC) ((unsigned*)(ws + WS_CDIST))[i] = F32_INF_BITS;
}

// ------------- K1 (split-K): partial[kslice] = x[:,ks*256:+256] @ W^T slice
// 256 thr/block, 8 rows x 4 cols/thread, BK=64, grid 512 (proven R11).
__global__ __launch_bounds__(256) void k1_split(const float* __restrict__ x,
                                                const float* __restrict__ W,
                                                float* __restrict__ ws) {
  __shared__ float xs[64][132];   // [k][row'] swizzled
  __shared__ float wls[64][68];   // [k][col]
  const int t = threadIdx.x;             // 0..255
  const int ks = blockIdx.x & 3;
  const int row0 = (blockIdx.x >> 2) * 128;
  const int kbase = ks * 256;
  const int tx = t & 15, ty = t >> 4;    // tx: 16 col-groups(x4), ty: 16 row-groups(x8)
  const int sseg = t & 15, srow = t >> 4;

  float4 px[8], pw[4];
  auto ld = [&](int kt) {
    const int kk = kbase + kt * 64;
    #pragma unroll
    for (int it = 0; it < 8; ++it)
      px[it] = *(const float4*)(x + (size_t)(row0 + srow + 16 * it) * DM + kk + sseg * 4);
    #pragma unroll
    for (int it = 0; it < 4; ++it)
      pw[it] = *(const float4*)(W + (size_t)(srow + 16 * it) * DM + kk + sseg * 4);
  };
  ld(0);

  float acc[8][4];
  #pragma unroll
  for (int i = 0; i < 8; i++)
    #pragma unroll
    for (int j = 0; j < 4; j++) acc[i][j] = 0.f;

  for (int kt = 0; kt < 4; ++kt) {
    __syncthreads();
    const int sg4 = sseg * 4;
    #pragma unroll
    for (int it = 0; it < 8; ++it) {
      const int cpos = (srow + 16 * it) ^ ((sseg & 3) << 3);
      xs[sg4 + 0][cpos] = px[it].x; xs[sg4 + 1][cpos] = px[it].y;
      xs[sg4 + 2][cpos] = px[it].z; xs[sg4 + 3][cpos] = px[it].w;
    }
    #pragma unroll
    for (int it = 0; it < 4; ++it) {
      const int wcol = srow + 16 * it;
      wls[sg4 + 0][wcol] = pw[it].x; wls[sg4 + 1][wcol] = pw[it].y;
      wls[sg4 + 2][wcol] = pw[it].z; wls[sg4 + 3][wcol] = pw[it].w;
    }
    __syncthreads();
    if (kt < 3) ld(kt + 1);

    #pragma unroll 8
    for (int dl = 0; dl < 64; ++dl) {
      const int xcol = (ty * 8) ^ (((dl >> 2) & 3) << 3);
      float4 xv0 = *(const float4*)(&xs[dl][xcol]);
      float4 xv1 = *(const float4*)(&xs[dl][xcol + 4]);
      float4 wv  = *(const float4*)(&wls[dl][tx * 4]);
      float xz[8] = {xv0.x, xv0.y, xv0.z, xv0.w, xv1.x, xv1.y, xv1.z, xv1.w};
      float wc[4] = {wv.x, wv.y, wv.z, wv.w};
      #pragma unroll
      for (int i = 0; i < 8; i++)
        #pragma unroll
        for (int j = 0; j < 4; j++)
          acc[i][j] = fmaf(xz[i], wc[j], acc[i][j]);
    }
  }

  float* part = ws + WS_PART + (size_t)ks * NROWS * CD;
  #pragma unroll
  for (int i = 0; i < 8; i++) {
    const int row = row0 + ty * 8 + i;
    float4 v; v.x = acc[i][0]; v.y = acc[i][1]; v.z = acc[i][2]; v.w = acc[i][3];
    *(float4*)(part + (size_t)row * CD + tx * 4) = v;
  }
}

// ------------- K1r: sum 4 partials + bias, row-normalize, write z/zn2
__global__ __launch_bounds__(256) void k1_reduce(const float* __restrict__ bdown,
                                                 float* __restrict__ ws) {
  const int t = threadIdx.x;
  const int tx = t & 15, ty = t >> 4;
  const int row = blockIdx.x * 16 + ty;
  const float* part = ws + WS_PART;
  const size_t off = (size_t)row * CD + tx * 4;

  float4 v0 = *(const float4*)(part + off);
  float4 v1 = *(const float4*)(part + (size_t)1 * NROWS * CD + off);
  float4 v2 = *(const float4*)(part + (size_t)2 * NROWS * CD + off);
  float4 v3 = *(const float4*)(part + (size_t)3 * NROWS * CD + off);
  float4 b  = *(const float4*)(bdown + tx * 4);
  float4 v;
  v.x = (v0.x + v1.x) + (v2.x + v3.x) + b.x;
  v.y = (v0.y + v1.y) + (v2.y + v3.y) + b.y;
  v.z = (v0.z + v1.z) + (v2.z + v3.z) + b.z;
  v.w = (v0.w + v1.w) + (v2.w + v3.w) + b.w;

  float ss = v.x * v.x + v.y * v.y + v.z * v.z + v.w * v.w;
  #pragma unroll
  for (int m = 1; m < 16; m <<= 1) ss += __shfl_xor(ss, m, 64);
  float inv = 1.0f / sqrtf(ss);   // uniform per-row scale: argmin-safe
  float4 zv; zv.x = v.x * inv; zv.y = v.y * inv; zv.z = v.z * inv; zv.w = v.w * inv;
  *(float4*)(ws + WS_Z + off) = zv;
  if (tx == 0) (ws + WS_ZN2)[row] = ss * inv * inv;
}

// ------------- K1 legacy (used only if ws too small for split-K partials)
__global__ __launch_bounds__(256) void k1_down(const float* __restrict__ x,
                                               const float* __restrict__ W,
                                               const float* __restrict__ bdown,
                                               float* __restrict__ ws) {
  __shared__ float xs[64][68];
  __shared__ float wls[64][68];
  const int t = threadIdx.x;
  const int row0 = blockIdx.x * 64;
  const int tx = t & 15, ty = t >> 4;

  int pr[4], pseg[4];
  #pragma unroll
  for (int it = 0; it < 4; ++it) { int c = t + it * 256; pr[it] = c >> 4; pseg[it] = c & 15; }

  float4 px[4], pw[4];
  #pragma unroll
  for (int it = 0; it < 4; ++it) {
    px[it] = *(const float4*)(x + (size_t)(row0 + pr[it]) * DM + pseg[it] * 4);
    pw[it] = *(const float4*)(W + (size_t)pr[it] * DM + pseg[it] * 4);
  }

  float acc[4][4];
  #pragma unroll
  for (int i = 0; i < 4; i++)
    #pragma unroll
    for (int j = 0; j < 4; j++) acc[i][j] = 0.f;

  for (int kt = 0; kt < 16; ++kt) {
    __syncthreads();
    #pragma unroll
    for (int it = 0; it < 4; ++it) {
      *(float4*)(&xs[pr[it]][pseg[it] * 4]) = px[it];
      *(float4*)(&wls[pr[it]][pseg[it] * 4]) = pw[it];
    }
    __syncthreads();
    if (kt < 15) {
      const int k0 = (kt + 1) * 64;
      #pragma unroll
      for (int it = 0; it < 4; ++it) {
        px[it] = *(const float4*)(x + (size_t)(row0 + pr[it]) * DM + k0 + pseg[it] * 4);
        pw[it] = *(const float4*)(W + (size_t)pr[it] * DM + k0 + pseg[it] * 4);
      }
    }
    #pragma unroll 4
    for (int k = 0; k < 64; k += 4) {
      float4 xv[4], wv[4];
      #pragma unroll
      for (int i = 0; i < 4; i++) xv[i] = *(const float4*)(&xs[ty * 4 + i][k]);
      #pragma unroll
      for (int j = 0; j < 4; j++) wv[j] = *(const float4*)(&wls[tx * 4 + j][k]);
      #pragma unroll
      for (int i = 0; i < 4; i++)
        #pragma unroll
        for (int j = 0; j < 4; j++)
          acc[i][j] = fmaf(xv[i].x, wv[j].x, fmaf(xv[i].y, wv[j].y,
                      fmaf(xv[i].z, wv[j].z, fmaf(xv[i].w, wv[j].w, acc[i][j]))));
    }
  }

  #pragma unroll
  for (int j = 0; j < 4; j++) {
    float bj = bdown[tx * 4 + j];
    #pragma unroll
    for (int i = 0; i < 4; i++) acc[i][j] += bj;
  }

  float* z = ws + WS_Z;
  float* zn2 = ws + WS_ZN2;
  #pragma unroll
  for (int i = 0; i < 4; i++) {
    float ss = acc[i][0] * acc[i][0] + acc[i][1] * acc[i][1] +
               acc[i][2] * acc[i][2] + acc[i][3] * acc[i][3];
    #pragma unroll
    for (int m = 1; m < 16; m <<= 1) ss += __shfl_xor(ss, m, 64);
    float inv = 1.0f / sqrtf(ss);
    float4 zv;
    zv.x = acc[i][0] * inv; zv.y = acc[i][1] * inv;
    zv.z = acc[i][2] * inv; zv.w = acc[i][3] * inv;
    int row = row0 + ty * 4 + i;
    *(float4*)(z + (size_t)row * CD + tx * 4) = zv;
    if (tx == 0) zn2[row] = ss * inv * inv;
  }
}

// ------------- K_CVT: z -> bf16 zb; cb -> bf16 cbb (pad 0); zero counters.
__global__ __launch_bounds__(256) void k_cvt(const float* __restrict__ cb,
                                             float* __restrict__ ws) {
  const int i = blockIdx.x * 256 + threadIdx.x;
  unsigned short u[8];
  if (i < NROWS * CD / 8) {
    const float* src = ws + WS_Z + (size_t)i * 8;
    #pragma unroll
    for (int e = 0; e < 8; ++e) u[e] = f2bf(src[e]);
    *(short8*)((unsigned short*)(ws + WS_ZB2) + (size_t)i * 8) = *(short8*)u;
  } else if (i < NROWS * CD / 8 + NC * CD / 8) {
    const int j = i - NROWS * CD / 8;
    #pragma unroll
    for (int e = 0; e < 8; ++e) {
      const int f = j * 8 + e;                    // cbb flat idx: code*64+d
      u[e] = (f < KC * CD) ? f2bf(cb[f + CD]) : (unsigned short)0;
    }
    *(short8*)((unsigned short*)(ws + WS_CBB2) + (size_t)j * 8) = *(short8*)u;
  } else if (i < NROWS * CD / 8 + NC * CD / 8 + NROWS * 4) {
    ((unsigned*)(ws + WS_CNT))[i - (NROWS * CD / 8 + NC * CD / 8)] = 0u;
  }
}

// ---- K2M v3: bf16 MFMA two-pass, LDS colmin (atomic-fix).
// Block = 8 waves x SAME code quarter; grid 512 = 128 row-octets x 4 quarters.
// Pass 1: row-min (regs) + colmin -> LDS (ds atomicMin, contention-free);
// ONE global atomicMin per (block, code) at the end: 2M -> 262K global atomics.
// Pass 2: re-run MFMAs, append codes with s <= rowmin+MARGIN to per-(row,
// quarter) candidate lists (>=1 per quarter: the quarter-min qualifies).
// Frag mapping identical to validated R12/R13 kernels.
__global__ __launch_bounds__(512) void k2m_dist(float* __restrict__ ws) {
  __shared__ unsigned colmin[512];
  const int t = threadIdx.x;
  const int l = t & 63;
  const int wv = t >> 6;                     // 0..7
  const int qt = blockIdx.x & 3;             // code quarter (same for all waves)
  const int ro = blockIdx.x >> 2;            // row octet 0..127
  const int rg = ro * 8 + wv;                // rowgroup 0..1023
  const int row0 = rg * 16;
  const int batch = row0 >> 11;
  const unsigned short* zb = (const unsigned short*)(ws + WS_ZB2);
  const unsigned short* cbb = (const unsigned short*)(ws + WS_CBB2);
  const float* cn2p = ws + WS_CN2;
  unsigned* cdist = (unsigned*)(ws + WS_CDIST) + (size_t)batch * KC;
  unsigned* cntp = (unsigned*)(ws + WS_CNT);
  unsigned* candl = (unsigned*)(ws + WS_CANDL);

  colmin[t] = F32_INF_BITS;
  __syncthreads();

  const int col = l & 15, kb = l >> 4;
  const size_t za = (size_t)(row0 + col) * CD + kb * 8;
  const short8 A0 = *(const short8*)(zb + za);
  const short8 A1 = *(const short8*)(zb + za + 32);

  float zn2q[4];
  #pragma unroll
  for (int q = 0; q < 4; ++q) zn2q[q] = (ws + WS_ZN2)[row0 + kb * 4 + q];

  const int tile0 = qt * 32;
  float rmin[4];
  #pragma unroll
  for (int q = 0; q < 4; ++q) rmin[q] = __uint_as_float(F32_INF_BITS);

  short8 B0, B1; float c2;
  {
    const size_t ca = (size_t)(tile0 * 16 + col) * CD + kb * 8;
    B0 = *(const short8*)(cbb + ca);
    B1 = *(const short8*)(cbb + ca + 32);
    c2 = cn2p[tile0 * 16 + col];
  }

  // ---- pass 1: per-row min + per-code column-min into LDS
  for (int tt = 0; tt < 32; ++tt) {
    const int tile = tile0 + tt;
    short8 nB0, nB1; float nc2 = 0.f;
    if (tt < 31) {
      const size_t ca = (size_t)((tile + 1) * 16 + col) * CD + kb * 8;
      nB0 = *(const short8*)(cbb + ca);
      nB1 = *(const short8*)(cbb + ca + 32);
      nc2 = cn2p[(tile + 1) * 16 + col];
    }
    f32x4 acc = {0.f, 0.f, 0.f, 0.f};
    acc = __builtin_amdgcn_mfma_f32_16x16x32_bf16(A0, B0, acc, 0, 0, 0);
    acc = __builtin_amdgcn_mfma_f32_16x16x32_bf16(A1, B1, acc, 0, 0, 0);
    float cmin = __uint_as_float(F32_INF_BITS);
    #pragma unroll
    for (int q = 0; q < 4; ++q) {
      const float s = fmaf(-2.f, acc[q], c2);
      rmin[q] = fminf(rmin[q], s);
      float v = zn2q[q] + s;
      v = v < 0.f ? 0.f : v;        // clamp(d2,0): monotone under sqrt/min
      cmin = fminf(cmin, v);
    }
    cmin = fminf(cmin, __shfl_xor(cmin, 16, 64));
    cmin = fminf(cmin, __shfl_xor(cmin, 32, 64));
    if (l < 16) atomicMin(&colmin[tt * 16 + col], __float_as_uint(cmin));
    B0 = nB0; B1 = nB1; c2 = nc2;
  }

  __syncthreads();
  {
    const int code = qt * 512 + t;   // t < 512
    if (code < KC) atomicMin(&cdist[code], colmin[t]);
  }

  // reduce rmin across the 16 cols (masks 1..8 stay within each kb-group)
  #pragma unroll
  for (int m = 1; m <= 8; m <<= 1)
    #pragma unroll
    for (int q = 0; q < 4; ++q)
      rmin[q] = fminf(rmin[q], __shfl_xor(rmin[q], m, 64));
  float thrq[4];
  #pragma unroll
  for (int q = 0; q < 4; ++q) thrq[q] = rmin[q] + MARGIN;

  // ---- pass 2: collect candidates within margin
  {
    const size_t ca = (size_t)(tile0 * 16 + col) * CD + kb * 8;
    B0 = *(const short8*)(cbb + ca);
    B1 = *(const short8*)(cbb + ca + 32);
    c2 = cn2p[tile0 * 16 + col];
  }
  for (int tt = 0; tt < 32; ++tt) {
    const int tile = tile0 + tt;
    short8 nB0, nB1; float nc2 = 0.f;
    if (tt < 31) {
      const size_t ca = (size_t)((tile + 1) * 16 + col) * CD + kb * 8;
      nB0 = *(const short8*)(cbb + ca);
      nB1 = *(const short8*)(cbb + ca + 32);
      nc2 = cn2p[(tile + 1) * 16 + col];
    }
    f32x4 acc = {0.f, 0.f, 0.f, 0.f};
    acc = __builtin_amdgcn_mfma_f32_16x16x32_bf16(A0, B0, acc, 0, 0, 0);
    acc = __builtin_amdgcn_mfma_f32_16x16x32_bf16(A1, B1, acc, 0, 0, 0);
    const int code = tile * 16 + col;
    if (code < KC) {
      #pragma unroll
      for (int q = 0; q < 4; ++q) {
        const float s = fmaf(-2.f, acc[q], c2);
        if (s <= thrq[q]) {
          const int row = row0 + kb * 4 + q;
          const unsigned slot = atomicAdd(&cntp[row * 4 + qt], 1u);
          if (slot < 32u) candl[(size_t)(row * 4 + qt) * 32 + slot] = (unsigned)code;
        }
      }
    }
    B0 = nB0; B1 = nB1; c2 = nc2;
  }
}

// ---- K2M-R v2: wave-per-row exact f32 rescore (lane-per-candidate).
// z hoisted to registers (float4 loads). f32 chain = d-ascending fmaf,
// identical to the proven f32 path; tie-break = lowest code = first occur.
__global__ __launch_bounds__(512) void k2m_rescore(const float* __restrict__ cb,
                                                   float* __restrict__ ws,
                                                   float* __restrict__ out) {
  const int t = threadIdx.x;
  const int l = t & 63;
  const int row = blockIdx.x * 8 + (t >> 6);   // grid 2048
  const unsigned* cntp = (const unsigned*)(ws + WS_CNT);
  const unsigned* candl = (const unsigned*)(ws + WS_CANDL);
  const float* zp = ws + WS_Z + (size_t)row * CD;
  const float* cn2p = ws + WS_CN2;

  float zr[64];
  #pragma unroll
  for (int c4 = 0; c4 < 16; ++c4) {
    float4 v = *(const float4*)(zp + c4 * 4);
    zr[c4 * 4 + 0] = v.x; zr[c4 * 4 + 1] = v.y;
    zr[c4 * 4 + 2] = v.z; zr[c4 * 4 + 3] = v.w;
  }

  float bv = __uint_as_float(F32_INF_BITS);
  int bi = 0x7FFFFFFF;
  #pragma unroll
  for (int q = 0; q < 4; ++q) {
    const unsigned cnt = min(cntp[row * 4 + q], 32u);
    if ((unsigned)l < cnt) {
      const int code = (int)candl[(size_t)(row * 4 + q) * 32 + l];
      const float* c = cb + (size_t)(code + 1) * CD;
      float dot = 0.f;
      #pragma unroll
      for (int d = 0; d < 64; ++d) dot = fmaf(zr[d], c[d], dot);
      const float sc = fmaf(-2.f, dot, cn2p[code]);
      if (sc < bv || (sc == bv && code < bi)) { bv = sc; bi = code; }
    }
  }
  #pragma unroll
  for (int m = 1; m < 64; m <<= 1) {
    const float ov = __shfl_xor(bv, m, 64);
    const int oi = __shfl_xor(bi, m, 64);
    if (ov < bv || (ov == bv && oi < bi)) { bv = ov; bi = oi; }
  }
  if (l == 0) {
    const int idx = bi + 1;
    ((int*)(ws + WS_IDXM2))[row] = idx;
    out[OUT_IDX + row] = (float)idx;
  }
}

// ---- K2 legacy f32 (fallback path; proven 70.7us)
__global__ __launch_bounds__(512) void k2_dist(const float* __restrict__ cbp,
                                               float* __restrict__ ws) {
  __shared__ float zT[64][132];
  __shared__ float cT[64][132];
  __shared__ float cn2s[128];
  __shared__ float zn2s[128];
  __shared__ unsigned colmin[128];

  const int t = threadIdx.x;
  const int gq = blockIdx.x & 3;
  const int rt = blockIdx.x >> 2;
  const int row0 = rt << 7;
  const int batch = rt >> 4;
  const int tx = t & 31, ty = t >> 5;
  const float* z = ws + WS_Z;
  const float* cn2p = ws + WS_CN2;
  unsigned* cdist = (unsigned*)(ws + WS_CDIST) + (size_t)batch * KC;

  if (t < 128) zn2s[t] = (ws + WS_ZN2)[row0 + t];

  {
    const int sr = t >> 2, sp = t & 3;
    float4 v[4];
    #pragma unroll
    for (int it = 0; it < 4; ++it)
      v[it] = *(const float4*)(z + (size_t)(row0 + sr) * CD + (sp + 4 * it) * 4);
    #pragma unroll
    for (int it = 0; it < 4; ++it) {
      const int sg4 = (sp + 4 * it) * 4;
      zT[sg4 + 0][sr] = v[it].x; zT[sg4 + 1][sr] = v[it].y;
      zT[sg4 + 2][sr] = v[it].z; zT[sg4 + 3][sr] = v[it].w;
    }
  }

  const int cr = t >> 2, cp = t & 3;
  const int ccol = cr ^ (((cr >> 5) & 3) << 2);
  float4 pc[4];
  auto ldc = [&](int lt) {
    const int code = gq * 512 + lt * 128 + cr;
    #pragma unroll
    for (int it = 0; it < 4; ++it)
      pc[it] = (code < KC) ? *(const float4*)(cbp + (size_t)(code + 1) * CD + (cp + 4 * it) * 4)
                           : make_float4(0.f, 0.f, 0.f, 0.f);
  };
  ldc(0);

  float bestv[8];
  int besti[8];
  #pragma unroll
  for (int i = 0; i < 8; i++) { bestv[i] = __uint_as_float(F32_INF_BITS); besti[i] = 0; }

  const int ccol0 = (tx * 4) ^ (((tx >> 3) & 3) << 2);

  for (int lt = 0; lt < 4; ++lt) {
    __syncthreads();
    #pragma unroll
    for (int it = 0; it < 4; ++it) {
      const int sg4 = (cp + 4 * it) * 4;
      cT[sg4 + 0][ccol] = pc[it].x; cT[sg4 + 1][ccol] = pc[it].y;
      cT[sg4 + 2][ccol] = pc[it].z; cT[sg4 + 3][ccol] = pc[it].w;
    }
    if (t < 128) {
      cn2s[t] = cn2p[gq * 512 + lt * 128 + t];
      colmin[t] = F32_INF_BITS;
    }
    __syncthreads();
    if (lt < 3) ldc(lt + 1);

    float acc[8][4];
    #pragma unroll
    for (int i = 0; i < 8; i++)
      #pragma unroll
      for (int j = 0; j < 4; j++) acc[i][j] = 0.f;

    #pragma unroll 8
    for (int d = 0; d < 64; ++d) {
      float4 za = *(const float4*)(&zT[d][ty * 8]);
      float4 zb = *(const float4*)(&zT[d][ty * 8 + 4]);
      float4 cv = *(const float4*)(&cT[d][ccol0]);
      float zz[8] = {za.x, za.y, za.z, za.w, zb.x, zb.y, zb.z, zb.w};
      float cc[4] = {cv.x, cv.y, cv.z, cv.w};
      #pragma unroll
      for (int i = 0; i < 8; i++)
        #pragma unroll
        for (int j = 0; j < 4; j++)
          acc[i][j] = fmaf(zz[i], cc[j], acc[i][j]);
    }

    const int jbase = gq * 512 + lt * 128;
    #pragma unroll
    for (int jl = 0; jl < 4; ++jl) {
      const int jloc = tx * 4 + jl;
      const int jg = jbase + jloc;
      const float c2 = cn2s[jloc];
      float colv = __uint_as_float(F32_INF_BITS);
      #pragma unroll
      for (int i = 0; i < 8; ++i) {
        float s = fmaf(-2.f, acc[i][jl], c2);
        if (s < bestv[i]) { bestv[i] = s; besti[i] = jg; }
        float v = zn2s[ty * 8 + i] + s;
        v = v < 0.f ? 0.f : v;
        colv = v < colv ? v : colv;
      }
      colv = fminf(colv, __shfl_xor(colv, 32, 64));
      if ((t & 32) == 0) atomicMin(&colmin[jloc], __float_as_uint(colv));
    }
    __syncthreads();
    if (t < 128) {
      const int jg2 = jbase + t;
      if (jg2 < KC) atomicMin(&cdist[jg2], colmin[t]);
    }
  }

  #pragma unroll
  for (int m = 1; m <= 16; m <<= 1) {
    #pragma unroll
    for (int i = 0; i < 8; i++) {
      float ov = __shfl_xor(bestv[i], m, 64);
      int oi = __shfl_xor(besti[i], m, 64);
      if (ov < bestv[i] || (ov == bestv[i] && oi < besti[i])) { bestv[i] = ov; besti[i] = oi; }
    }
  }
  if (tx == 0) {
    #pragma unroll
    for (int i = 0; i < 8; i++) {
      const int row = row0 + ty * 8 + i;
      (ws + WS_BV)[(size_t)gq * NROWS + row] = bestv[i];
      ((int*)(ws + WS_BI))[(size_t)gq * NROWS + row] = besti[i] + 1;
    }
  }
}

// ------- K3M: gather + commitment + scatter, idx precomputed (MFMA path)
__global__ __launch_bounds__(256) void k3m_scatter(const float* __restrict__ cb,
                                                   float* __restrict__ ws,
                                                   float* __restrict__ out) {
  const int t = threadIdx.x;
  const int lane = t & 63;
  const int w = t >> 6;
  const int rowbase = blockIdx.x * 32 + w * 8;
  const float* z = ws + WS_Z;

  const int myidx = ((const int*)(ws + WS_IDXM2))[rowbase + (lane & 7)];

  float sq = 0.f;
  #pragma unroll
  for (int r = 0; r < 8; ++r) {
    const int idx = __shfl(myidx, r, 8);
    const int row = rowbase + r;
    const float c = cb[(size_t)idx * CD + lane];
    const float zv = z[(size_t)row * CD + lane];
    out[OUT_HARD + (size_t)row * CD + lane] = zv + (c - zv);
    const float d = c - zv;
    sq = fmaf(d, d, sq);
    atomicAdd(ws + WS_SUMS + (size_t)idx * CD + lane, zv);
    if (lane == 0) atomicAdd((unsigned*)(ws + WS_BINC) + idx, 1u);
  }

  __shared__ float red[4];
  #pragma unroll
  for (int m = 1; m < 64; m <<= 1) sq += __shfl_xor(sq, m, 64);
  if (lane == 0) red[w] = sq;
  __syncthreads();
  if (t == 0) (ws + WS_COMMIT)[blockIdx.x] = red[0] + red[1] + red[2] + red[3];
}

// ------- K3 legacy: inline quarter-argmin merge + gather + scatter
__global__ __launch_bounds__(256) void k3_scatter(const float* __restrict__ cb,
                                                  float* __restrict__ ws,
                                                  float* __restrict__ out) {
  const int t = threadIdx.x;
  const int lane = t & 63;
  const int w = t >> 6;
  const int rowbase = blockIdx.x * 32 + w * 8;
  const float* z = ws + WS_Z;

  const int myrow = rowbase + (lane & 7);
  float bv = (ws + WS_BV)[myrow];
  int myidx = ((const int*)(ws + WS_BI))[myrow];
  #pragma unroll
  for (int g2 = 1; g2 < 4; ++g2) {
    float v = (ws + WS_BV)[(size_t)g2 * NROWS + myrow];
    int i2 = ((const int*)(ws + WS_BI))[(size_t)g2 * NROWS + myrow];
    if (v < bv) { bv = v; myidx = i2; }
  }
  if (lane < 8) out[OUT_IDX + myrow] = (float)myidx;

  float sq = 0.f;
  #pragma unroll
  for (int r = 0; r < 8; ++r) {
    const int idx = __shfl(myidx, r, 8);
    const int row = rowbase + r;
    const float c = cb[(size_t)idx * CD + lane];
    const float zv = z[(size_t)row * CD + lane];
    out[OUT_HARD + (size_t)row * CD + lane] = zv + (c - zv);
    const float d = c - zv;
    sq = fmaf(d, d, sq);
    atomicAdd(ws + WS_SUMS + (size_t)idx * CD + lane, zv);
    if (lane == 0) atomicAdd((unsigned*)(ws + WS_BINC) + idx, 1u);
  }

  __shared__ float red[4];
  #pragma unroll
  for (int m = 1; m < 64; m <<= 1) sq += __shfl_xor(sq, m, 64);
  if (lane == 0) red[w] = sq;
  __syncthreads();
  if (t == 0) (ws + WS_COMMIT)[blockIdx.x] = red[0] + red[1] + red[2] + red[3];
}

// --------- K4a: new_cs + n + losses (single block, small data only)
__global__ __launch_bounds__(1024) void k4a_stats(const float* __restrict__ cs_in,
                                                  float* __restrict__ ws,
                                                  float* __restrict__ out) {
  __shared__ float red[1024];
  const int t = threadIdx.x;
  const unsigned* binc = (const unsigned*)(ws + WS_BINC);

  float npart = 0.f;
  #pragma unroll
  for (int i = t; i < NC; i += 1024) {
    float nc = DECAY * cs_in[i] + (1.f - DECAY) * (float)binc[i];
    out[OUT_CS + i] = nc;
    npart += nc;
  }
  red[t] = npart; __syncthreads();
  for (int s = 512; s > 0; s >>= 1) { if (t < s) red[t] += red[t + s]; __syncthreads(); }
  if (t == 0) (ws + WS_N)[0] = red[0];
  __syncthreads();

  float cpart = 0.f;
  for (int j = t; j < K3_BLOCKS; j += 1024) cpart += (ws + WS_COMMIT)[j];
  red[t] = cpart; __syncthreads();
  for (int s = 512; s > 0; s >>= 1) { if (t < s) red[t] += red[t + s]; __syncthreads(); }
  float commit = red[0]; __syncthreads();

  const unsigned* cdist = (const unsigned*)(ws + WS_CDIST);
  float lsum = 0.f, ccount = 0.f;
  for (int j = t; j < KC; j += 1024) {
    if (binc[j + 1] == 0u) {
      ccount += 1.f;
      float srow = 0.f;
      #pragma unroll
      for (int b = 0; b < NB; b++) srow += sqrtf(__uint_as_float(cdist[b * KC + j]));
      lsum += srow;
    }
  }
  red[t] = lsum; __syncthreads();
  for (int s = 512; s > 0; s >>= 1) { if (t < s) red[t] += red[t + s]; __syncthreads(); }
  float totloss = red[0]; __syncthreads();
  red[t] = ccount; __syncthreads();
  for (int s = 512; s > 0; s >>= 1) { if (t < s) red[t] += red[t + s]; __syncthreads(); }
  float cnt = red[0] * (float)NB;
  if (t == 0) {
    out[OUT_COMMIT] = commit / (float)(NROWS * CD);
    out[OUT_EMB] = totloss / fmaxf(cnt, 1.f);
  }
}

// --------- K4b: new_csum, centroids, new_cb (512 blocks x 256)
__global__ __launch_bounds__(256) void k4b_update(const float* __restrict__ cb,
                                                  const float* __restrict__ csum_in,
                                                  const float* __restrict__ ws,
                                                  float* __restrict__ out) {
  const int e = blockIdx.x * 256 + threadIdx.x;   // 0 .. NC*CD-1
  const int k = e >> 6;
  const unsigned* binc = (const unsigned*)(ws + WS_BINC);
  const float n = (ws + WS_N)[0];
  const float denom = n + (float)NC * 1e-5f;

  float ncsum = DECAY * csum_in[e] + (1.f - DECAY) * (ws + WS_SUMS)[e];
  out[OUT_CSUM + e] = ncsum;
  float smoothed = (out[OUT_CS + k] + 1e-5f) * n / denom;
  float cent = ncsum / smoothed;
  float v = (binc[k] != 0u) ? cent : cb[e];
  if (k == 0) v = 0.f;
  out[OUT_CB + e] = v;
}

extern "C" void kernel_launch(void* const* d_in, const int* in_sizes, int n_in,
                              void* d_out, int out_size, void* d_ws, size_t ws_size,
                              hipStream_t stream) {
  const float* x    = (const float*)d_in[0];
  const float* W    = (const float*)d_in[1];
  const float* b    = (const float*)d_in[2];
  const float* cb   = (const float*)d_in[3];
  const float* cs   = (const float*)d_in[4];
  const float* csum = (const float*)d_in[5];
  float* out = (float*)d_out;
  float* ws  = (float*)d_ws;

  const size_t need = ((size_t)WS_PART + (size_t)4 * NROWS * CD) * sizeof(float);
  const bool use_split = ws_size >= need;   // host-side, deterministic

  hipLaunchKernelGGL(k0_init, dim3(512), dim3(256), 0, stream, cb, ws);
  if (use_split) {
    hipLaunchKernelGGL(k1_split,  dim3(512),  dim3(256), 0, stream, x, W, ws);
    hipLaunchKernelGGL(k1_reduce, dim3(1024), dim3(256), 0, stream, b, ws);
    // MFMA path (scratch aliases PART region)
    hipLaunchKernelGGL(k_cvt,       dim3(832),       dim3(256), 0, stream, cb, ws);
    hipLaunchKernelGGL(k2m_dist,    dim3(512),       dim3(512), 0, stream, ws);
    hipLaunchKernelGGL(k2m_rescore, dim3(2048),      dim3(512), 0, stream, cb, ws, out);
    hipLaunchKernelGGL(k3m_scatter, dim3(K3_BLOCKS), dim3(256), 0, stream, cb, ws, out);
  } else {
    hipLaunchKernelGGL(k1_down,    dim3(256),       dim3(256), 0, stream, x, W, b, ws);
    hipLaunchKernelGGL(k2_dist,    dim3(512),       dim3(512), 0, stream, cb, ws);
    hipLaunchKernelGGL(k3_scatter, dim3(K3_BLOCKS), dim3(256), 0, stream, cb, ws, out);
  }
  hipLaunchKernelGGL(k4a_stats,  dim3(1),   dim3(1024), 0, stream, cs, ws, out);
  hipLaunchKernelGGL(k4b_update, dim3(512), dim3(256),  0, stream, cb, csum, ws, out);
}

// Round 15
// 133.482 us; speedup vs baseline: 1.7762x; 1.3999x over previous
//
#include <hip/hip_runtime.h>

// Problem constants
#define NROWS 16384   // 8*2048 tokens
#define DM    1024    // d_model
#define CD    64      // code depth
#define NC    2048    // num codes
#define KC    2047    // codes excluding index 0
#define NB    8       // batch
#define DECAY 0.99f

#define K3_BLOCKS 512

// d_out layout (floats, concatenated in reference return order)
#define OUT_HARD   0
#define OUT_IDX    1048576
#define OUT_COMMIT 1064960
#define OUT_EMB    1064961
#define OUT_CB     1064962
#define OUT_CS     1196034
#define OUT_CSUM   1198082

// d_ws layout (float offsets)
#define WS_Z      0                          // 1048576 f
#define WS_CN2    1048576                    // 2048 f ([2047]=+INF pad)
#define WS_BINC   1050624                    // 2048 u32
#define WS_SUMS   1052672                    // 131072 f
#define WS_CDIST  1183744                    // 8*2047 u32
#define WS_COMMIT 1200120                    // 512 f per-block partials
#define WS_ZN2    1200632                    // 16384 f
#define WS_N      1217016                    // 1 f (+3 pad)
#define WS_PART   1298940                    // 4*16384*64 f split-K partials (k1 only)
// k2 scratch ALIASES the PART region (k1 partials are dead by k2-launch):
#define WS_BV     WS_PART                    // 4*16384 f  per-quarter best value
#define WS_BI     (WS_PART + 65536)          // 4*16384 i32 per-quarter best idx (+1)

#define F32_INF_BITS 0x7F800000u

// ---------------------------------------------------------------- K0: init
__global__ __launch_bounds__(256) void k0_init(const float* __restrict__ cb,
                                               float* __restrict__ ws) {
  int i = blockIdx.x * 256 + threadIdx.x;
  if (i < NC * CD) (ws + WS_SUMS)[i] = 0.0f;
  if (i < NC) {
    ((unsigned*)(ws + WS_BINC))[i] = 0u;
    float cn2;
    if (i < KC) {
      const float* c = cb + (size_t)(i + 1) * CD;
      float s0 = 0.f, s1 = 0.f;
      #pragma unroll
      for (int d = 0; d < CD; d += 2) { s0 = fmaf(c[d], c[d], s0); s1 = fmaf(c[d+1], c[d+1], s1); }
      cn2 = s0 + s1;
    } else {
      cn2 = __uint_as_float(F32_INF_BITS);
    }
    (ws + WS_CN2)[i] = cn2;
  }
  if (i < NB * KC) ((unsigned*)(ws + WS_CDIST))[i] = F32_INF_BITS;
}

// ------------- K1 (split-K): partial[kslice] = x[:,ks*256:+256] @ W^T slice
// v2: 256 thr/block, 8 rows x 4 cols/thread (k2's proven read geometry),
// BK=64, grid 512 = 128 rowtiles x 4 kslices -> 2 blocks/CU x 4 waves =
// 8 waves/CU with cross-block barrier overlap.
__global__ __launch_bounds__(256) void k1_split(const float* __restrict__ x,
                                                const float* __restrict__ W,
                                                float* __restrict__ ws) {
  __shared__ float xs[64][132];   // [k][row'] swizzled
  __shared__ float wls[64][68];   // [k][col]
  const int t = threadIdx.x;             // 0..255
  const int ks = blockIdx.x & 3;
  const int row0 = (blockIdx.x >> 2) * 128;
  const int kbase = ks * 256;
  const int tx = t & 15, ty = t >> 4;    // tx: 16 col-groups(x4), ty: 16 row-groups(x8)
  const int sseg = t & 15, srow = t >> 4; // staging: seg 0..15 (4k each), row-base 0..15

  float4 px[8], pw[4];
  auto ld = [&](int kt) {
    const int kk = kbase + kt * 64;
    #pragma unroll
    for (int it = 0; it < 8; ++it)
      px[it] = *(const float4*)(x + (size_t)(row0 + srow + 16 * it) * DM + kk + sseg * 4);
    #pragma unroll
    for (int it = 0; it < 4; ++it)
      pw[it] = *(const float4*)(W + (size_t)(srow + 16 * it) * DM + kk + sseg * 4);
  };
  ld(0);

  float acc[8][4];
  #pragma unroll
  for (int i = 0; i < 8; i++)
    #pragma unroll
    for (int j = 0; j < 4; j++) acc[i][j] = 0.f;

  for (int kt = 0; kt < 4; ++kt) {
    __syncthreads();
    const int sg4 = sseg * 4;
    #pragma unroll
    for (int it = 0; it < 8; ++it) {
      const int cpos = (srow + 16 * it) ^ ((sseg & 3) << 3);   // matches read swz ((dl>>2)&3)
      xs[sg4 + 0][cpos] = px[it].x; xs[sg4 + 1][cpos] = px[it].y;
      xs[sg4 + 2][cpos] = px[it].z; xs[sg4 + 3][cpos] = px[it].w;
    }
    #pragma unroll
    for (int it = 0; it < 4; ++it) {
      const int wcol = srow + 16 * it;
      wls[sg4 + 0][wcol] = pw[it].x; wls[sg4 + 1][wcol] = pw[it].y;
      wls[sg4 + 2][wcol] = pw[it].z; wls[sg4 + 3][wcol] = pw[it].w;
    }
    __syncthreads();
    if (kt < 3) ld(kt + 1);

    #pragma unroll 8
    for (int dl = 0; dl < 64; ++dl) {
      const int xcol = (ty * 8) ^ (((dl >> 2) & 3) << 3);
      float4 xv0 = *(const float4*)(&xs[dl][xcol]);
      float4 xv1 = *(const float4*)(&xs[dl][xcol + 4]);
      float4 wv  = *(const float4*)(&wls[dl][tx * 4]);
      float xz[8] = {xv0.x, xv0.y, xv0.z, xv0.w, xv1.x, xv1.y, xv1.z, xv1.w};
      float wc[4] = {wv.x, wv.y, wv.z, wv.w};
      #pragma unroll
      for (int i = 0; i < 8; i++)
        #pragma unroll
        for (int j = 0; j < 4; j++)
          acc[i][j] = fmaf(xz[i], wc[j], acc[i][j]);
    }
  }

  float* part = ws + WS_PART + (size_t)ks * NROWS * CD;
  #pragma unroll
  for (int i = 0; i < 8; i++) {
    const int row = row0 + ty * 8 + i;
    float4 v; v.x = acc[i][0]; v.y = acc[i][1]; v.z = acc[i][2]; v.w = acc[i][3];
    *(float4*)(part + (size_t)row * CD + tx * 4) = v;
  }
}

// ------------- K1r: sum 4 partials + bias, row-normalize, write z/zn2
__global__ __launch_bounds__(256) void k1_reduce(const float* __restrict__ bdown,
                                                 float* __restrict__ ws) {
  const int t = threadIdx.x;
  const int tx = t & 15, ty = t >> 4;
  const int row = blockIdx.x * 16 + ty;
  const float* part = ws + WS_PART;
  const size_t off = (size_t)row * CD + tx * 4;

  float4 v0 = *(const float4*)(part + off);
  float4 v1 = *(const float4*)(part + (size_t)1 * NROWS * CD + off);
  float4 v2 = *(const float4*)(part + (size_t)2 * NROWS * CD + off);
  float4 v3 = *(const float4*)(part + (size_t)3 * NROWS * CD + off);
  float4 b  = *(const float4*)(bdown + tx * 4);
  float4 v;
  v.x = (v0.x + v1.x) + (v2.x + v3.x) + b.x;
  v.y = (v0.y + v1.y) + (v2.y + v3.y) + b.y;
  v.z = (v0.z + v1.z) + (v2.z + v3.z) + b.z;
  v.w = (v0.w + v1.w) + (v2.w + v3.w) + b.w;

  float ss = v.x * v.x + v.y * v.y + v.z * v.z + v.w * v.w;
  #pragma unroll
  for (int m = 1; m < 16; m <<= 1) ss += __shfl_xor(ss, m, 64);
  float inv = 1.0f / sqrtf(ss);   // uniform per-row scale: argmin-safe
  float4 zv; zv.x = v.x * inv; zv.y = v.y * inv; zv.z = v.z * inv; zv.w = v.w * inv;
  *(float4*)(ws + WS_Z + off) = zv;
  if (tx == 0) (ws + WS_ZN2)[row] = ss * inv * inv;
}

// ------------- K1 legacy (used only if ws too small for split-K partials)
__global__ __launch_bounds__(256) void k1_down(const float* __restrict__ x,
                                               const float* __restrict__ W,
                                               const float* __restrict__ bdown,
                                               float* __restrict__ ws) {
  __shared__ float xs[64][68];
  __shared__ float wls[64][68];
  const int t = threadIdx.x;
  const int row0 = blockIdx.x * 64;
  const int tx = t & 15, ty = t >> 4;

  int pr[4], pseg[4];
  #pragma unroll
  for (int it = 0; it < 4; ++it) { int c = t + it * 256; pr[it] = c >> 4; pseg[it] = c & 15; }

  float4 px[4], pw[4];
  #pragma unroll
  for (int it = 0; it < 4; ++it) {
    px[it] = *(const float4*)(x + (size_t)(row0 + pr[it]) * DM + pseg[it] * 4);
    pw[it] = *(const float4*)(W + (size_t)pr[it] * DM + pseg[it] * 4);
  }

  float acc[4][4];
  #pragma unroll
  for (int i = 0; i < 4; i++)
    #pragma unroll
    for (int j = 0; j < 4; j++) acc[i][j] = 0.f;

  for (int kt = 0; kt < 16; ++kt) {
    __syncthreads();
    #pragma unroll
    for (int it = 0; it < 4; ++it) {
      *(float4*)(&xs[pr[it]][pseg[it] * 4]) = px[it];
      *(float4*)(&wls[pr[it]][pseg[it] * 4]) = pw[it];
    }
    __syncthreads();
    if (kt < 15) {
      const int k0 = (kt + 1) * 64;
      #pragma unroll
      for (int it = 0; it < 4; ++it) {
        px[it] = *(const float4*)(x + (size_t)(row0 + pr[it]) * DM + k0 + pseg[it] * 4);
        pw[it] = *(const float4*)(W + (size_t)pr[it] * DM + k0 + pseg[it] * 4);
      }
    }
    #pragma unroll 4
    for (int k = 0; k < 64; k += 4) {
      float4 xv[4], wv[4];
      #pragma unroll
      for (int i = 0; i < 4; i++) xv[i] = *(const float4*)(&xs[ty * 4 + i][k]);
      #pragma unroll
      for (int j = 0; j < 4; j++) wv[j] = *(const float4*)(&wls[tx * 4 + j][k]);
      #pragma unroll
      for (int i = 0; i < 4; i++)
        #pragma unroll
        for (int j = 0; j < 4; j++)
          acc[i][j] = fmaf(xv[i].x, wv[j].x, fmaf(xv[i].y, wv[j].y,
                      fmaf(xv[i].z, wv[j].z, fmaf(xv[i].w, wv[j].w, acc[i][j]))));
    }
  }

  #pragma unroll
  for (int j = 0; j < 4; j++) {
    float bj = bdown[tx * 4 + j];
    #pragma unroll
    for (int i = 0; i < 4; i++) acc[i][j] += bj;
  }

  float* z = ws + WS_Z;
  float* zn2 = ws + WS_ZN2;
  #pragma unroll
  for (int i = 0; i < 4; i++) {
    float ss = acc[i][0] * acc[i][0] + acc[i][1] * acc[i][1] +
               acc[i][2] * acc[i][2] + acc[i][3] * acc[i][3];
    #pragma unroll
    for (int m = 1; m < 16; m <<= 1) ss += __shfl_xor(ss, m, 64);
    float inv = 1.0f / sqrtf(ss);
    float4 zv;
    zv.x = acc[i][0] * inv; zv.y = acc[i][1] * inv;
    zv.z = acc[i][2] * inv; zv.w = acc[i][3] * inv;
    int row = row0 + ty * 4 + i;
    *(float4*)(z + (size_t)row * CD + tx * 4) = zv;
    if (tx == 0) zn2[row] = ss * inv * inv;
  }
}

// ---- K2: distance GEMM + per-row argmin (per 512-code quarter) + column-min
// EXACT R8/R10/R11 kernel (proven 70.7us, VALUBusy 61%, occ 38.8%): z resident
// full-d, per-tile c staging + reg prefetch, 3 barriers/tile, 8 rows x 4
// codes, grid 512 = 2 blocks/CU (16 waves/CU).
__global__ __launch_bounds__(512) void k2_dist(const float* __restrict__ cbp,
                                               float* __restrict__ ws) {
  __shared__ float zT[64][132];   // [d][row 0..127]
  __shared__ float cT[64][132];   // [d][code']
  __shared__ float cn2s[128];
  __shared__ float zn2s[128];
  __shared__ unsigned colmin[128];

  const int t = threadIdx.x;
  const int gq = blockIdx.x & 3;           // code quarter: 512 codes
  const int rt = blockIdx.x >> 2;          // 0..127 rowtile
  const int row0 = rt << 7;                // 128 rows
  const int batch = rt >> 4;               // 16 rowtiles per batch
  const int tx = t & 31, ty = t >> 5;      // tx: 32 code-groups(x4), ty: 16 row-groups(x8)
  const float* z = ws + WS_Z;
  const float* cn2p = ws + WS_CN2;
  unsigned* cdist = (unsigned*)(ws + WS_CDIST) + (size_t)batch * KC;

  if (t < 128) zn2s[t] = (ws + WS_ZN2)[row0 + t];

  // stage zT once: 128 rows x 64 d; 4 threads/row, 4 segs (16 d) each
  {
    const int sr = t >> 2, sp = t & 3;
    float4 v[4];
    #pragma unroll
    for (int it = 0; it < 4; ++it)
      v[it] = *(const float4*)(z + (size_t)(row0 + sr) * CD + (sp + 4 * it) * 4);
    #pragma unroll
    for (int it = 0; it < 4; ++it) {
      const int sg4 = (sp + 4 * it) * 4;
      zT[sg4 + 0][sr] = v[it].x; zT[sg4 + 1][sr] = v[it].y;
      zT[sg4 + 2][sr] = v[it].z; zT[sg4 + 3][sr] = v[it].w;
    }
  }

  // c staging geometry: 128 codes/tile, 4 threads/code, 4 segs each
  const int cr = t >> 2, cp = t & 3;
  const int ccol = cr ^ (((cr >> 5) & 3) << 2);   // swizzled cT column
  float4 pc[4];
  auto ldc = [&](int lt) {
    const int code = gq * 512 + lt * 128 + cr;    // 0-based in [0,2048)
    #pragma unroll
    for (int it = 0; it < 4; ++it)
      pc[it] = (code < KC) ? *(const float4*)(cbp + (size_t)(code + 1) * CD + (cp + 4 * it) * 4)
                           : make_float4(0.f, 0.f, 0.f, 0.f);
  };
  ldc(0);

  float bestv[8];
  int besti[8];
  #pragma unroll
  for (int i = 0; i < 8; i++) { bestv[i] = __uint_as_float(F32_INF_BITS); besti[i] = 0; }

  const int ccol0 = (tx * 4) ^ (((tx >> 3) & 3) << 2);   // read col for 4 codes

  for (int lt = 0; lt < 4; ++lt) {
    __syncthreads();   // prev tile fully drained (and zT ready on first iter)
    #pragma unroll
    for (int it = 0; it < 4; ++it) {
      const int sg4 = (cp + 4 * it) * 4;
      cT[sg4 + 0][ccol] = pc[it].x; cT[sg4 + 1][ccol] = pc[it].y;
      cT[sg4 + 2][ccol] = pc[it].z; cT[sg4 + 3][ccol] = pc[it].w;
    }
    if (t < 128) {
      cn2s[t] = cn2p[gq * 512 + lt * 128 + t];   // [2047] = +INF pad
      colmin[t] = F32_INF_BITS;
    }
    __syncthreads();
    if (lt < 3) ldc(lt + 1);       // prefetch next tile's codes into regs

    float acc[8][4];
    #pragma unroll
    for (int i = 0; i < 8; i++)
      #pragma unroll
      for (int j = 0; j < 4; j++) acc[i][j] = 0.f;

    #pragma unroll 8
    for (int d = 0; d < 64; ++d) {
      float4 za = *(const float4*)(&zT[d][ty * 8]);
      float4 zb = *(const float4*)(&zT[d][ty * 8 + 4]);
      float4 cv = *(const float4*)(&cT[d][ccol0]);
      float zz[8] = {za.x, za.y, za.z, za.w, zb.x, zb.y, zb.z, zb.w};
      float cc[4] = {cv.x, cv.y, cv.z, cv.w};
      #pragma unroll
      for (int i = 0; i < 8; i++)
        #pragma unroll
        for (int j = 0; j < 4; j++)
          acc[i][j] = fmaf(zz[i], cc[j], acc[i][j]);
    }

    // epilogue: score = cn2 - 2*dot (zn2 const per row: argmin-equivalent)
    const int jbase = gq * 512 + lt * 128;
    #pragma unroll
    for (int jl = 0; jl < 4; ++jl) {
      const int jloc = tx * 4 + jl;
      const int jg = jbase + jloc;
      const float c2 = cn2s[jloc];
      float colv = __uint_as_float(F32_INF_BITS);
      #pragma unroll
      for (int i = 0; i < 8; ++i) {
        float s = fmaf(-2.f, acc[i][jl], c2);
        if (s < bestv[i]) { bestv[i] = s; besti[i] = jg; }  // (lt,jl) ascending: first-index ties
        float v = zn2s[ty * 8 + i] + s;
        v = v < 0.f ? 0.f : v;          // clamp(d2,0): monotone under sqrt/min
        colv = v < colv ? v : colv;
      }
      // reduce colv across the 2 ty values in this wave (lane ^32 shares tx)
      colv = fminf(colv, __shfl_xor(colv, 32, 64));
      if ((t & 32) == 0) atomicMin(&colmin[jloc], __float_as_uint(colv));
    }
    __syncthreads();
    if (t < 128) {
      const int jg2 = jbase + t;
      if (jg2 < KC) atomicMin(&cdist[jg2], colmin[t]);
    }
  }

  // argmin reduce across the 32 tx lanes (masks 1..16 stay within same ty)
  #pragma unroll
  for (int m = 1; m <= 16; m <<= 1) {
    #pragma unroll
    for (int i = 0; i < 8; i++) {
      float ov = __shfl_xor(bestv[i], m, 64);
      int oi = __shfl_xor(besti[i], m, 64);
      if (ov < bestv[i] || (ov == bestv[i] && oi < besti[i])) { bestv[i] = ov; besti[i] = oi; }
    }
  }
  if (tx == 0) {
    #pragma unroll
    for (int i = 0; i < 8; i++) {
      const int row = row0 + ty * 8 + i;
      (ws + WS_BV)[(size_t)gq * NROWS + row] = bestv[i];
      ((int*)(ws + WS_BI))[(size_t)gq * NROWS + row] = besti[i] + 1;
    }
  }
}

// ------- K3: inline quarter-argmin merge + gather hard codes + commitment
//         partials + scatter sums/bincounts (k2b fused in).
__global__ __launch_bounds__(256) void k3_scatter(const float* __restrict__ cb,
                                                  float* __restrict__ ws,
                                                  float* __restrict__ out) {
  const int t = threadIdx.x;
  const int lane = t & 63;
  const int w = t >> 6;
  const int rowbase = blockIdx.x * 32 + w * 8;
  const float* z = ws + WS_Z;

  // inline merge of the 4 quarter-argmins (ascending quarters, strict < ->
  // lowest quarter wins ties = first occurrence; identical to old k2b).
  const int myrow = rowbase + (lane & 7);
  float bv = (ws + WS_BV)[myrow];
  int myidx = ((const int*)(ws + WS_BI))[myrow];
  #pragma unroll
  for (int g2 = 1; g2 < 4; ++g2) {
    float v = (ws + WS_BV)[(size_t)g2 * NROWS + myrow];
    int i2 = ((const int*)(ws + WS_BI))[(size_t)g2 * NROWS + myrow];
    if (v < bv) { bv = v; myidx = i2; }
  }
  if (lane < 8) out[OUT_IDX + myrow] = (float)myidx;

  float sq = 0.f;
  #pragma unroll
  for (int r = 0; r < 8; ++r) {
    const int idx = __shfl(myidx, r, 8);   // idx for row rowbase+r (group-uniform)
    const int row = rowbase + r;
    const float c = cb[(size_t)idx * CD + lane];
    const float zv = z[(size_t)row * CD + lane];
    out[OUT_HARD + (size_t)row * CD + lane] = zv + (c - zv);  // matches z + sg(hard - z)
    const float d = c - zv;
    sq = fmaf(d, d, sq);
    atomicAdd(ws + WS_SUMS + (size_t)idx * CD + lane, zv);
    if (lane == 0) atomicAdd((unsigned*)(ws + WS_BINC) + idx, 1u);
  }

  __shared__ float red[4];
  #pragma unroll
  for (int m = 1; m < 64; m <<= 1) sq += __shfl_xor(sq, m, 64);
  if (lane == 0) red[w] = sq;
  __syncthreads();
  if (t == 0) (ws + WS_COMMIT)[blockIdx.x] = red[0] + red[1] + red[2] + red[3];
}

// --------- K4a: new_cs + n + losses (single block, small data only)
__global__ __launch_bounds__(1024) void k4a_stats(const float* __restrict__ cs_in,
                                                  float* __restrict__ ws,
                                                  float* __restrict__ out) {
  __shared__ float red[1024];
  const int t = threadIdx.x;
  const unsigned* binc = (const unsigned*)(ws + WS_BINC);

  float npart = 0.f;
  #pragma unroll
  for (int i = t; i < NC; i += 1024) {
    float nc = DECAY * cs_in[i] + (1.f - DECAY) * (float)binc[i];
    out[OUT_CS + i] = nc;
    npart += nc;
  }
  red[t] = npart; __syncthreads();
  for (int s = 512; s > 0; s >>= 1) { if (t < s) red[t] += red[t + s]; __syncthreads(); }
  if (t == 0) (ws + WS_N)[0] = red[0];
  __syncthreads();

  float cpart = 0.f;
  for (int j = t; j < K3_BLOCKS; j += 1024) cpart += (ws + WS_COMMIT)[j];
  red[t] = cpart; __syncthreads();
  for (int s = 512; s > 0; s >>= 1) { if (t < s) red[t] += red[t + s]; __syncthreads(); }
  float commit = red[0]; __syncthreads();

  const unsigned* cdist = (const unsigned*)(ws + WS_CDIST);
  float lsum = 0.f, ccount = 0.f;
  for (int j = t; j < KC; j += 1024) {
    if (binc[j + 1] == 0u) {
      ccount += 1.f;
      float srow = 0.f;
      #pragma unroll
      for (int b = 0; b < NB; b++) srow += sqrtf(__uint_as_float(cdist[b * KC + j]));
      lsum += srow;
    }
  }
  red[t] = lsum; __syncthreads();
  for (int s = 512; s > 0; s >>= 1) { if (t < s) red[t] += red[t + s]; __syncthreads(); }
  float totloss = red[0]; __syncthreads();
  red[t] = ccount; __syncthreads();
  for (int s = 512; s > 0; s >>= 1) { if (t < s) red[t] += red[t + s]; __syncthreads(); }
  float cnt = red[0] * (float)NB;
  if (t == 0) {
    out[OUT_COMMIT] = commit / (float)(NROWS * CD);
    out[OUT_EMB] = totloss / fmaxf(cnt, 1.f);
  }
}

// --------- K4b: new_csum, centroids, new_cb (512 blocks x 256)
__global__ __launch_bounds__(256) void k4b_update(const float* __restrict__ cb,
                                                  const float* __restrict__ csum_in,
                                                  const float* __restrict__ ws,
                                                  float* __restrict__ out) {
  const int e = blockIdx.x * 256 + threadIdx.x;   // 0 .. NC*CD-1
  const int k = e >> 6;
  const unsigned* binc = (const unsigned*)(ws + WS_BINC);
  const float n = (ws + WS_N)[0];
  const float denom = n + (float)NC * 1e-5f;

  float ncsum = DECAY * csum_in[e] + (1.f - DECAY) * (ws + WS_SUMS)[e];
  out[OUT_CSUM + e] = ncsum;
  float smoothed = (out[OUT_CS + k] + 1e-5f) * n / denom;
  float cent = ncsum / smoothed;
  float v = (binc[k] != 0u) ? cent : cb[e];
  if (k == 0) v = 0.f;
  out[OUT_CB + e] = v;
}

extern "C" void kernel_launch(void* const* d_in, const int* in_sizes, int n_in,
                              void* d_out, int out_size, void* d_ws, size_t ws_size,
                              hipStream_t stream) {
  const float* x    = (const float*)d_in[0];
  const float* W    = (const float*)d_in[1];
  const float* b    = (const float*)d_in[2];
  const float* cb   = (const float*)d_in[3];
  const float* cs   = (const float*)d_in[4];
  const float* csum = (const float*)d_in[5];
  float* out = (float*)d_out;
  float* ws  = (float*)d_ws;

  // split-K path needs partials: (WS_PART + 4*NROWS*CD) floats
  const size_t need = ((size_t)WS_PART + (size_t)4 * NROWS * CD) * sizeof(float);
  const bool use_split = ws_size >= need;   // host-side, deterministic

  hipLaunchKernelGGL(k0_init, dim3(512), dim3(256), 0, stream, cb, ws);
  if (use_split) {
    hipLaunchKernelGGL(k1_split,  dim3(512),  dim3(256), 0, stream, x, W, ws);
    hipLaunchKernelGGL(k1_reduce, dim3(1024), dim3(256), 0, stream, b, ws);
  } else {
    hipLaunchKernelGGL(k1_down, dim3(256), dim3(256), 0, stream, x, W, b, ws);
  }
  hipLaunchKernelGGL(k2_dist,   dim3(512),       dim3(512),  0, stream, cb, ws);
  hipLaunchKernelGGL(k3_scatter,dim3(K3_BLOCKS), dim3(256),  0, stream, cb, ws, out);
  hipLaunchKernelGGL(k4a_stats, dim3(1),         dim3(1024), 0, stream, cs, ws, out);
  hipLaunchKernelGGL(k4b_update,dim3(512),       dim3(256),  0, stream, cb, csum, ws, out);
}